// Round 10
// baseline (1718.112 us; speedup 1.0000x reference)
//
#include <hip/hip_runtime.h>
#include <hip/hip_bf16.h>

#define NT    10
#define NN    2048   // n_neurons
#define CA3C  2048
#define SEQ   1024
#define SPARS 0.05f
#define LRC   0.01f

typedef float          f32x4  __attribute__((ext_vector_type(4)));
typedef short          bf16x8 __attribute__((ext_vector_type(8)));
typedef unsigned short u16x4  __attribute__((ext_vector_type(4)));
typedef unsigned short u16x8  __attribute__((ext_vector_type(8)));

__device__ __forceinline__ unsigned short f2bf(float f) {   // RNE float->bf16 bits
    unsigned u = __float_as_uint(f);
    u += 0x7FFFu + ((u >> 16) & 1u);
    return (unsigned short)(u >> 16);
}
__device__ __forceinline__ float bf2f(unsigned short h) {
    return __uint_as_float(((unsigned)h) << 16);
}

// ---------------- Phase A: hippo_input (exact in bf16: values k*0.5, k<=30) --------
__global__ __launch_bounds__(256) void k_hippo(const int* __restrict__ tok,
        const float* __restrict__ sdr, const float* __restrict__ pos,
        unsigned short* __restrict__ Hh) {
    int s = blockIdx.x;
    int n = (blockIdx.y * 256 + threadIdx.x) * 4;
    const float* sp = sdr + (long)tok[s] * (NT * NN) + n;
    const float* pp = pos + (long)s * (NT * NN) + n;
    float a0 = 0.f, a1 = 0.f, a2 = 0.f, a3 = 0.f;
    #pragma unroll
    for (int t = 0; t < NT; ++t) {
        float4 sv = *(const float4*)(sp + t * NN);
        float4 pv = *(const float4*)(pp + t * NN);
        if (sv.x < SPARS) a0 += (pv.x < SPARS) ? 1.5f : 1.0f;
        if (sv.y < SPARS) a1 += (pv.y < SPARS) ? 1.5f : 1.0f;
        if (sv.z < SPARS) a2 += (pv.z < SPARS) ? 1.5f : 1.0f;
        if (sv.w < SPARS) a3 += (pv.w < SPARS) ? 1.5f : 1.0f;
    }
    u16x4 o = { f2bf(a0), f2bf(a1), f2bf(a2), f2bf(a3) };
    *(u16x4*)(Hh + (long)s * NN + n) = o;
}

// ---------------- split fp32 -> bf16 hi (+ optional lo residual) -------------------
__global__ __launch_bounds__(256) void k_split(const float* __restrict__ src,
        unsigned short* __restrict__ hi, unsigned short* __restrict__ lo) {
    long i = ((long)blockIdx.x * 256 + threadIdx.x) * 8;
    f32x4 x0 = *(const f32x4*)(src + i);
    f32x4 x1 = *(const f32x4*)(src + i + 4);
    float xs[8] = {x0.x, x0.y, x0.z, x0.w, x1.x, x1.y, x1.z, x1.w};
    u16x8 h, l;
    #pragma unroll
    for (int j = 0; j < 8; ++j) {
        unsigned short hb = f2bf(xs[j]);
        h[j] = hb;
        l[j] = f2bf(xs[j] - bf2f(hb));
    }
    *(u16x8*)(hi + i) = h;
    if (lo) *(u16x8*)(lo + i) = l;
}

// ---------------- MFMA GEMM: C[M][N] = A @ B^T, bf16 inputs, fp32 accum ------------
#define SPLIT_NONE 0
#define SPLIT_A    1
#define SPLIT_B    2

template<int MODE>
__global__ __launch_bounds__(256, 1) void k_mgemm(
        const unsigned short* __restrict__ A0, const unsigned short* __restrict__ A1,
        const unsigned short* __restrict__ Bh, const unsigned short* __restrict__ B1,
        float* __restrict__ C, int M, int N, int K,
        const float* __restrict__ Wadd, const float* __restrict__ af) {
    __shared__ unsigned short LA[4096], LB[4096], LX[4096];   // 8 KB each
    int tid = threadIdx.x, wid = tid >> 6, l = tid & 63;
    int m0 = blockIdx.y * 128, n0 = blockIdx.x * 128;
    int wr = wid >> 1, wc = wid & 1;
    int fr = l & 15, fk = l >> 4;
    f32x4 acc[4][4] = {};
    constexpr int NCH = (MODE == SPLIT_NONE) ? 16 : 24;   // 1KB chunks per k-tile
    constexpr int PW  = NCH / 4;
    for (int k0 = 0; k0 < K; k0 += 32) {
        __syncthreads();                                  // prior reads done
        #pragma unroll
        for (int i = 0; i < PW; ++i) {
            int cid = wid * PW + i;
            int arr = cid >> 3, ch = cid & 7;
            int kb = ch >> 1, row = (ch & 1) * 64 + l;
            const unsigned short* g; unsigned short* ld;
            if (arr == 0)      { g = A0 + (long)(m0 + row) * K; ld = LA; }
            else if (arr == 1) { g = Bh + (long)(n0 + row) * K; ld = LB; }
            else {
                if (MODE == SPLIT_A) g = A1 + (long)(m0 + row) * K;
                else                 g = B1 + (long)(n0 + row) * K;
                ld = LX;
            }
            __builtin_amdgcn_global_load_lds(
                (const __attribute__((address_space(1))) unsigned int*)(g + k0 + kb * 8),
                (__attribute__((address_space(3))) unsigned int*)(ld + kb * 1024 + (ch & 1) * 512),
                16, 0, 0);
        }
        __syncthreads();                                  // staging landed
        bf16x8 a0[4], b0[4], xf[4];
        #pragma unroll
        for (int t = 0; t < 4; ++t) {
            a0[t] = *(const bf16x8*)&LA[(fk * 128 + wr * 64 + t * 16 + fr) * 8];
            b0[t] = *(const bf16x8*)&LB[(fk * 128 + wc * 64 + t * 16 + fr) * 8];
            if (MODE == SPLIT_A) xf[t] = *(const bf16x8*)&LX[(fk * 128 + wr * 64 + t * 16 + fr) * 8];
            if (MODE == SPLIT_B) xf[t] = *(const bf16x8*)&LX[(fk * 128 + wc * 64 + t * 16 + fr) * 8];
        }
        #pragma unroll
        for (int mt = 0; mt < 4; ++mt)
            #pragma unroll
            for (int nt = 0; nt < 4; ++nt) {
                acc[mt][nt] = __builtin_amdgcn_mfma_f32_16x16x32_bf16(a0[mt], b0[nt], acc[mt][nt], 0, 0, 0);
                if (MODE == SPLIT_A)
                    acc[mt][nt] = __builtin_amdgcn_mfma_f32_16x16x32_bf16(xf[mt], b0[nt], acc[mt][nt], 0, 0, 0);
                if (MODE == SPLIT_B)
                    acc[mt][nt] = __builtin_amdgcn_mfma_f32_16x16x32_bf16(a0[mt], xf[nt], acc[mt][nt], 0, 0, 0);
            }
    }
    int drb = (l >> 4) * 4;
    #pragma unroll
    for (int mt = 0; mt < 4; ++mt)
        #pragma unroll
        for (int nt = 0; nt < 4; ++nt)
            #pragma unroll
            for (int e = 0; e < 4; ++e) {
                int row = m0 + wr * 64 + mt * 16 + drb + e;
                int cc  = n0 + wc * 64 + nt * 16 + (l & 15);
                float v = acc[mt][nt][e];
                if (Wadd) v = fmaf(af[row], Wadd[(long)row * N + cc], v);
                C[(long)row * N + cc] = v;
            }
}

// ---------------- fp64 re-check of near-zero dots (sign safety) --------------------
__global__ __launch_bounds__(256) void k_fixup(const unsigned short* __restrict__ Hh,
        const float* __restrict__ w, float* __restrict__ dots) {
    long i = (long)blockIdx.x * 256 + threadIdx.x;
    float d = dots[i];
    if (fabsf(d) < 1e-3f) {
        int s = (int)(i / CA3C), c = (int)(i % CA3C);
        const unsigned short* hr = Hh + (long)s * NN;
        const float* wr = w + (long)c * NN;
        double acc = 0.0;
        for (int n = 0; n < NN; ++n) acc += (double)bf2f(hr[n]) * (double)wr[n];
        dots[i] = (acc > 0.0) ? 1.0f : -1.0f;   // only the sign is consumed
    }
}

// ---------------- pack: preT[w][s] bits, popf[s], dense Xb bf16 (0/1 exact) --------
__global__ __launch_bounds__(64) void k_pack(const float* __restrict__ dots,
        unsigned* __restrict__ preT, float* __restrict__ popf,
        unsigned short* __restrict__ Xb) {
    int s = blockIdx.x;
    int w = threadIdx.x;
    const float* row = dots + (long)s * CA3C + w * 32;
    unsigned short* xrow = Xb + (long)s * CA3C + w * 32;
    unsigned m = 0;
    #pragma unroll
    for (int j4 = 0; j4 < 8; ++j4) {
        f32x4 v = *(const f32x4*)(row + j4 * 4);
        u16x4 xb;
        xb.x = v.x > 0.f ? 0x3F80 : 0; xb.y = v.y > 0.f ? 0x3F80 : 0;
        xb.z = v.z > 0.f ? 0x3F80 : 0; xb.w = v.w > 0.f ? 0x3F80 : 0;
        m |= (v.x > 0.f ? 1u : 0u) << (j4 * 4 + 0);
        m |= (v.y > 0.f ? 1u : 0u) << (j4 * 4 + 1);
        m |= (v.z > 0.f ? 1u : 0u) << (j4 * 4 + 2);
        m |= (v.w > 0.f ? 1u : 0u) << (j4 * 4 + 3);
        *(u16x4*)(xrow + j4 * 4) = xb;
    }
    preT[w * SEQ + s] = m;
    int pc = __popc(m);
    #pragma unroll
    for (int o = 1; o < 64; o <<= 1) pc += __shfl_xor(pc, o, 64);
    if (w == 0) popf[s] = (float)pc;
}

// ---------------- post bits per row: postT[r][32 words over steps 0..1022] ---------
__global__ __launch_bounds__(256) void k_packpost(const float* __restrict__ dots,
        unsigned* __restrict__ postT) {
    int r = blockIdx.x * 256 + threadIdx.x;    // 0..2047
    #pragma unroll 1
    for (int wi = 0; wi < 32; ++wi) {
        unsigned m = 0;
        int jmax = (wi == 31) ? 31 : 32;       // steps s = wi*32+j, s <= 1022
        for (int j = 0; j < jmax; ++j) {
            int s = wi * 32 + j;
            m |= (dots[(long)(s + 1) * CA3C + r] > 0.0f ? 1u : 0u) << j;
        }
        postT[r * 32 + wi] = m;
    }
}

// ---------------- transpose Xb[s][n] -> XbT[n][s] (bf16) ---------------------------
__global__ __launch_bounds__(256) void k_transpose(const unsigned short* __restrict__ Xb,
        unsigned short* __restrict__ XbT) {
    __shared__ unsigned short t[64][72];
    int s0 = blockIdx.x * 64, n0 = blockIdx.y * 64;
    int tx = threadIdx.x & 63, ty = threadIdx.x >> 6;
    #pragma unroll
    for (int ii = 0; ii < 16; ++ii) {
        int i = ty + ii * 4;
        t[i][tx] = Xb[(long)(s0 + i) * CA3C + n0 + tx];
    }
    __syncthreads();
    #pragma unroll
    for (int ii = 0; ii < 16; ++ii) {
        int i = ty + ii * 4;
        XbT[(long)(n0 + i) * SEQ + s0 + tx] = t[tx][i];
    }
}

// ---------------- Gram matrix G[i][j] = x_i . x_j via popcount (fp32 out) ----------
__global__ __launch_bounds__(256) void k_gram(const unsigned* __restrict__ preT,
        float* __restrict__ G) {
    int i = blockIdx.x;
    int t = threadIdx.x;
    int a0 = 0, a1 = 0, a2 = 0, a3 = 0;
    #pragma unroll 8
    for (int w = 0; w < 64; ++w) {
        unsigned ri = preT[w * SEQ + i];       // uniform -> broadcast
        const unsigned* pr = preT + w * SEQ;
        a0 += __popc(ri & pr[t]);
        a1 += __popc(ri & pr[t + 256]);
        a2 += __popc(ri & pr[t + 512]);
        a3 += __popc(ri & pr[t + 768]);
    }
    long base = (long)i * SEQ;
    G[base + t] = (float)a0;       G[base + t + 256] = (float)a1;
    G[base + t + 512] = (float)a2; G[base + t + 768] = (float)a3;
}

// ---------------- DPP-based full-wave (64 lane) sum; broadcast via lane 63 ---------
__device__ __forceinline__ float wave_sum64(float x) {
    #define DPPADD(ctrl, rmask) \
        x += __int_as_float(__builtin_amdgcn_update_dpp(0, __float_as_int(x), ctrl, rmask, 0xF, true))
    DPPADD(0xB1, 0xF);
    DPPADD(0x4E, 0xF);
    DPPADD(0x141, 0xF);
    DPPADD(0x140, 0xF);
    DPPADD(0x142, 0xA);
    DPPADD(0x143, 0xC);
    #undef DPPADD
    return __int_as_float(__builtin_amdgcn_readlane(__float_as_int(x), 63));
}

// ---------------- Phase D (Gram form, RIGHT-LOOKING): scalar recurrence per row ----
// R8 had a backward stream (7680 loads chained into acc -> latency-bound, 454us).
// Now each wave keeps its row's FUTURE contributions in 15 named regs A1..A15:
//   A_k = sum_{b'<k} sum_j c_j * G[64b'+j][64k+lane]
// After block b's j-loop, a rank-64 forward update folds block-b coefficients into
// A_{b+1..15}. Loads are independent (ILP hides L2 latency); c_j==0 steps are
// skipped via wave-uniform scalar branch (~halves G traffic). At block b:
// acc = s0*B0 + A_b. Rescale events scale A* too (same V-space invariant).
__global__ __launch_bounds__(256) void k_scan2(const float* __restrict__ W0,
        const float* __restrict__ B0, const float* __restrict__ G,
        const unsigned* __restrict__ postT, const float* __restrict__ popf,
        float* __restrict__ coef, float* __restrict__ alphaf) {
    __shared__ float Gd[64][68];
    __shared__ float ctab[4][1024];
    int wid = threadIdx.x >> 6, lane = threadIdx.x & 63;
    int r = blockIdx.x * 4 + wid;
    #pragma unroll
    for (int kk = 0; kk < 16; ++kk) ctab[wid][kk * 64 + lane] = 0.f;
    const float* wr = W0 + (long)r * NN + lane * 32;
    f32x4 q0 = *(const f32x4*)(wr +  0), q1 = *(const f32x4*)(wr +  4);
    f32x4 q2 = *(const f32x4*)(wr +  8), q3 = *(const f32x4*)(wr + 12);
    f32x4 q4 = *(const f32x4*)(wr + 16), q5 = *(const f32x4*)(wr + 20);
    f32x4 q6 = *(const f32x4*)(wr + 24), q7 = *(const f32x4*)(wr + 28);
    f32x4 pp = q0*q0 + q1*q1 + q2*q2 + q3*q3 + q4*q4 + q5*q5 + q6*q6 + q7*q7;
    float nu = wave_sum64((pp.x + pp.y) + (pp.z + pp.w));
    float alpha = 1.f, inv_alpha = 1.f;
    { float t = fmaxf(nu, 1.f); alpha *= rsqrtf(t); inv_alpha *= sqrtf(t); nu = fminf(nu, 1.f); }
    float s0 = 1.f;
    float A1 = 0.f, A2 = 0.f, A3 = 0.f, A4 = 0.f, A5 = 0.f, A6 = 0.f, A7 = 0.f,
          A8 = 0.f, A9 = 0.f, A10 = 0.f, A11 = 0.f, A12 = 0.f, A13 = 0.f,
          A14 = 0.f, A15 = 0.f;

    for (int b = 0; b < 16; ++b) {
        __syncthreads();
        {   // cooperative stage of G diag block [64b..64b+63]^2
            int gi = threadIdx.x >> 2, gj = (threadIdx.x & 3) * 16;
            const float* gs = G + (long)(b * 64 + gi) * SEQ + b * 64 + gj;
            *(f32x4*)&Gd[gi][gj +  0] = *(const f32x4*)(gs +  0);
            *(f32x4*)&Gd[gi][gj +  4] = *(const f32x4*)(gs +  4);
            *(f32x4*)&Gd[gi][gj +  8] = *(const f32x4*)(gs +  8);
            *(f32x4*)&Gd[gi][gj + 12] = *(const f32x4*)(gs + 12);
        }
        __syncthreads();
        float myB0  = B0[(long)r * SEQ + b * 64 + lane];
        float mypop = popf[b * 64 + lane];
        unsigned long long pm;
        {   unsigned lo = postT[r * 32 + 2 * b], hi = postT[r * 32 + 2 * b + 1];
            pm = ((unsigned long long)(unsigned)__builtin_amdgcn_readfirstlane((int)hi) << 32)
               |  (unsigned long long)(unsigned)__builtin_amdgcn_readfirstlane((int)lo);
        }
        float accin = 0.f;
        #define RDA(K) if (b == K) accin = A##K;
        RDA(1) RDA(2) RDA(3) RDA(4) RDA(5) RDA(6) RDA(7) RDA(8)
        RDA(9) RDA(10) RDA(11) RDA(12) RDA(13) RDA(14) RDA(15)
        #undef RDA
        float acc = fmaf(s0, myB0, accin);
        float cj = 0.f;
        #pragma unroll
        for (int j = 0; j < 64; ++j) {
            if ((pm >> j) & 1ull) {          // wave-uniform branch
                float dot = __int_as_float(__builtin_amdgcn_readlane(__float_as_int(acc), j));
                float pj  = __int_as_float(__builtin_amdgcn_readlane(__float_as_int(mypop), j));
                float c = LRC * inv_alpha;
                nu = fmaf(2.f * LRC, alpha * dot, fmaf(LRC * LRC, pj, nu));
                float t = fmaxf(nu, 1.f);
                alpha *= rsqrtf(t); inv_alpha *= sqrtf(t); nu = fminf(nu, 1.f);
                acc = fmaf(c, Gd[j][lane], acc);     // fold step j into this block's future
                cj = (lane == j) ? c : cj;
            }
        }
        ctab[wid][b * 64 + lane] = cj;
        // forward (right-looking) update: A_K += sum_j c_j * G[64b+j][64K+lane], K>b
        #define UPDK(K) \
        if (K > b) { \
            float u0 = 0.f, u1 = 0.f, u2 = 0.f, u3 = 0.f; \
            const float* gk = G + (long)(b * 64) * SEQ + K * 64 + lane; \
            _Pragma("unroll 4") \
            for (int j = 0; j < 64; ++j) { \
                float cjv = __int_as_float(__builtin_amdgcn_readlane(__float_as_int(cj), j)); \
                if (cjv != 0.f) { \
                    float gv = gk[(long)j * SEQ]; \
                    if ((j & 3) == 0)      u0 = fmaf(cjv, gv, u0); \
                    else if ((j & 3) == 1) u1 = fmaf(cjv, gv, u1); \
                    else if ((j & 3) == 2) u2 = fmaf(cjv, gv, u2); \
                    else                   u3 = fmaf(cjv, gv, u3); \
                } \
            } \
            A##K += (u0 + u1) + (u2 + u3); \
        }
        UPDK(1) UPDK(2) UPDK(3) UPDK(4) UPDK(5) UPDK(6) UPDK(7) UPDK(8)
        UPDK(9) UPDK(10) UPDK(11) UPDK(12) UPDK(13) UPDK(14) UPDK(15)
        #undef UPDK
        if (inv_alpha > 1e10f) {             // rescale event: fold alpha into V-space
            #pragma unroll 1
            for (int kk = 0; kk <= b; ++kk) ctab[wid][kk * 64 + lane] *= alpha;
            A1 *= alpha; A2 *= alpha; A3 *= alpha; A4 *= alpha; A5 *= alpha;
            A6 *= alpha; A7 *= alpha; A8 *= alpha; A9 *= alpha; A10 *= alpha;
            A11 *= alpha; A12 *= alpha; A13 *= alpha; A14 *= alpha; A15 *= alpha;
            s0 *= alpha; alpha = 1.f; inv_alpha = 1.f;
        }
    }
    if (lane == 0) alphaf[r] = alpha * s0;
    #pragma unroll
    for (int kk = 0; kk < 16; ++kk)
        coef[(long)r * SEQ + kk * 64 + lane] = alpha * ctab[wid][kk * 64 + lane];
}

extern "C" void kernel_launch(void* const* d_in, const int* in_sizes, int n_in,
                              void* d_out, int out_size, void* d_ws, size_t ws_size,
                              hipStream_t stream) {
    const int*   tok     = (const int*)d_in[0];
    const float* sdr     = (const float*)d_in[1];
    const float* pos     = (const float*)d_in[2];
    const float* w_hippo = (const float*)d_in[3];
    const float* assoc   = (const float*)d_in[4];
    float* out = (float*)d_out;

    char* ws = (char*)d_ws;
    // Slot map (36.6 MB total, aliased by lifetime):
    unsigned short* Hh  = (unsigned short*)(ws);                 // 0-4 MB (dead after fixup)
    float*          G   = (float*)(ws);                          //   then G (gram, 4 MB)
    unsigned short* Wh  = (unsigned short*)(ws + (4l << 20));    // 4-12 MB (dead after dots)
    unsigned short* Sh  = Wh;                                    //   then assoc-bf16
    unsigned short* Ch  = Wh;                                    //   then coef-hi (4 MB)
    unsigned short* Cl  = (unsigned short*)(ws + (8l << 20));    //   coef-lo   (4 MB)
    unsigned short* Wl  = (unsigned short*)(ws + (12l << 20));   // 12-20 MB (dead after dots)
    float*          coef= (float*)(ws + (12l << 20));            //   then coef fp32 (8 MB)
    float*          dots= (float*)(ws + (20l << 20));            // 20-28 MB (dead after pack)
    float*          B0f = dots;                                  //   then B0 (8 MB)
    unsigned short* Xb  = (unsigned short*)(ws + (28l << 20));   // 28-32 MB
    unsigned short* XbT = (unsigned short*)(ws + (32l << 20));   // 32-36 MB
    unsigned* preT   = (unsigned*)(ws + (36l << 20));            // 256 KB
    unsigned* postT  = (unsigned*)(ws + (36l << 20) + 262144);   // 256 KB
    float*    popf   = (float*)(ws + (36l << 20) + 524288);      // 4 KB
    float*    alphaf = (float*)(ws + (36l << 20) + 532480);      // 8 KB

    k_hippo            <<<dim3(SEQ, 2),   256, 0, stream>>>(tok, sdr, pos, Hh);
    k_split            <<<2048,           256, 0, stream>>>(w_hippo, Wh, Wl);
    k_mgemm<SPLIT_B>   <<<dim3(16, 8),    256, 0, stream>>>(Hh, nullptr, Wh, Wl, dots,
                                                            1024, 2048, 2048, nullptr, nullptr);
    k_fixup            <<<8192,           256, 0, stream>>>(Hh, w_hippo, dots);
    k_pack             <<<SEQ,             64, 0, stream>>>(dots, preT, popf, Xb);
    k_packpost         <<<8,              256, 0, stream>>>(dots, postT);
    k_transpose        <<<dim3(16, 32),   256, 0, stream>>>(Xb, XbT);
    k_gram             <<<SEQ,            256, 0, stream>>>(preT, G);
    k_split            <<<2048,           256, 0, stream>>>(assoc, Sh, nullptr);
    k_mgemm<SPLIT_NONE><<<dim3(8, 16),    256, 0, stream>>>(Sh, nullptr, Xb, nullptr, B0f,
                                                            2048, 1024, 2048, nullptr, nullptr);
    k_scan2            <<<512,            256, 0, stream>>>(assoc, B0f, G, postT, popf, coef, alphaf);
    k_split            <<<1024,           256, 0, stream>>>(coef, Ch, Cl);
    k_mgemm<SPLIT_A>   <<<dim3(16, 16),   256, 0, stream>>>(Ch, Cl, XbT, nullptr, out,
                                                            2048, 2048, 1024, assoc, alphaf);
}

// Round 11
// 928.683 us; speedup vs baseline: 1.8501x; 1.8501x over previous
//
#include <hip/hip_runtime.h>
#include <hip/hip_bf16.h>

#define NT    10
#define NN    2048   // n_neurons
#define CA3C  2048
#define SEQ   1024
#define SPARS 0.05f
#define LRC   0.01f

typedef float          f32x4  __attribute__((ext_vector_type(4)));
typedef short          bf16x8 __attribute__((ext_vector_type(8)));
typedef unsigned short u16x4  __attribute__((ext_vector_type(4)));
typedef unsigned short u16x8  __attribute__((ext_vector_type(8)));

__device__ __forceinline__ unsigned short f2bf(float f) {   // RNE float->bf16 bits
    unsigned u = __float_as_uint(f);
    u += 0x7FFFu + ((u >> 16) & 1u);
    return (unsigned short)(u >> 16);
}
__device__ __forceinline__ float bf2f(unsigned short h) {
    return __uint_as_float(((unsigned)h) << 16);
}

// ---------------- Phase A: hippo_input (exact in bf16: values k*0.5, k<=30) --------
__global__ __launch_bounds__(256) void k_hippo(const int* __restrict__ tok,
        const float* __restrict__ sdr, const float* __restrict__ pos,
        unsigned short* __restrict__ Hh) {
    int s = blockIdx.x;
    int n = (blockIdx.y * 256 + threadIdx.x) * 4;
    const float* sp = sdr + (long)tok[s] * (NT * NN) + n;
    const float* pp = pos + (long)s * (NT * NN) + n;
    float a0 = 0.f, a1 = 0.f, a2 = 0.f, a3 = 0.f;
    #pragma unroll
    for (int t = 0; t < NT; ++t) {
        float4 sv = *(const float4*)(sp + t * NN);
        float4 pv = *(const float4*)(pp + t * NN);
        if (sv.x < SPARS) a0 += (pv.x < SPARS) ? 1.5f : 1.0f;
        if (sv.y < SPARS) a1 += (pv.y < SPARS) ? 1.5f : 1.0f;
        if (sv.z < SPARS) a2 += (pv.z < SPARS) ? 1.5f : 1.0f;
        if (sv.w < SPARS) a3 += (pv.w < SPARS) ? 1.5f : 1.0f;
    }
    u16x4 o = { f2bf(a0), f2bf(a1), f2bf(a2), f2bf(a3) };
    *(u16x4*)(Hh + (long)s * NN + n) = o;
}

// ---------------- split fp32 -> bf16 hi (+ optional lo residual) -------------------
__global__ __launch_bounds__(256) void k_split(const float* __restrict__ src,
        unsigned short* __restrict__ hi, unsigned short* __restrict__ lo) {
    long i = ((long)blockIdx.x * 256 + threadIdx.x) * 8;
    f32x4 x0 = *(const f32x4*)(src + i);
    f32x4 x1 = *(const f32x4*)(src + i + 4);
    float xs[8] = {x0.x, x0.y, x0.z, x0.w, x1.x, x1.y, x1.z, x1.w};
    u16x8 h, l;
    #pragma unroll
    for (int j = 0; j < 8; ++j) {
        unsigned short hb = f2bf(xs[j]);
        h[j] = hb;
        l[j] = f2bf(xs[j] - bf2f(hb));
    }
    *(u16x8*)(hi + i) = h;
    if (lo) *(u16x8*)(lo + i) = l;
}

// ---------------- MFMA GEMM: C[M][N] = A @ B^T, bf16 inputs, fp32 accum ------------
#define SPLIT_NONE 0
#define SPLIT_A    1
#define SPLIT_B    2

template<int MODE>
__global__ __launch_bounds__(256, 1) void k_mgemm(
        const unsigned short* __restrict__ A0, const unsigned short* __restrict__ A1,
        const unsigned short* __restrict__ Bh, const unsigned short* __restrict__ B1,
        float* __restrict__ C, int M, int N, int K,
        const float* __restrict__ Wadd, const float* __restrict__ af) {
    __shared__ unsigned short LA[4096], LB[4096], LX[4096];   // 8 KB each
    int tid = threadIdx.x, wid = tid >> 6, l = tid & 63;
    int m0 = blockIdx.y * 128, n0 = blockIdx.x * 128;
    int wr = wid >> 1, wc = wid & 1;
    int fr = l & 15, fk = l >> 4;
    f32x4 acc[4][4] = {};
    constexpr int NCH = (MODE == SPLIT_NONE) ? 16 : 24;   // 1KB chunks per k-tile
    constexpr int PW  = NCH / 4;
    for (int k0 = 0; k0 < K; k0 += 32) {
        __syncthreads();                                  // prior reads done
        #pragma unroll
        for (int i = 0; i < PW; ++i) {
            int cid = wid * PW + i;
            int arr = cid >> 3, ch = cid & 7;
            int kb = ch >> 1, row = (ch & 1) * 64 + l;
            const unsigned short* g; unsigned short* ld;
            if (arr == 0)      { g = A0 + (long)(m0 + row) * K; ld = LA; }
            else if (arr == 1) { g = Bh + (long)(n0 + row) * K; ld = LB; }
            else {
                if (MODE == SPLIT_A) g = A1 + (long)(m0 + row) * K;
                else                 g = B1 + (long)(n0 + row) * K;
                ld = LX;
            }
            __builtin_amdgcn_global_load_lds(
                (const __attribute__((address_space(1))) unsigned int*)(g + k0 + kb * 8),
                (__attribute__((address_space(3))) unsigned int*)(ld + kb * 1024 + (ch & 1) * 512),
                16, 0, 0);
        }
        __syncthreads();                                  // staging landed
        bf16x8 a0[4], b0[4], xf[4];
        #pragma unroll
        for (int t = 0; t < 4; ++t) {
            a0[t] = *(const bf16x8*)&LA[(fk * 128 + wr * 64 + t * 16 + fr) * 8];
            b0[t] = *(const bf16x8*)&LB[(fk * 128 + wc * 64 + t * 16 + fr) * 8];
            if (MODE == SPLIT_A) xf[t] = *(const bf16x8*)&LX[(fk * 128 + wr * 64 + t * 16 + fr) * 8];
            if (MODE == SPLIT_B) xf[t] = *(const bf16x8*)&LX[(fk * 128 + wc * 64 + t * 16 + fr) * 8];
        }
        #pragma unroll
        for (int mt = 0; mt < 4; ++mt)
            #pragma unroll
            for (int nt = 0; nt < 4; ++nt) {
                acc[mt][nt] = __builtin_amdgcn_mfma_f32_16x16x32_bf16(a0[mt], b0[nt], acc[mt][nt], 0, 0, 0);
                if (MODE == SPLIT_A)
                    acc[mt][nt] = __builtin_amdgcn_mfma_f32_16x16x32_bf16(xf[mt], b0[nt], acc[mt][nt], 0, 0, 0);
                if (MODE == SPLIT_B)
                    acc[mt][nt] = __builtin_amdgcn_mfma_f32_16x16x32_bf16(a0[mt], xf[nt], acc[mt][nt], 0, 0, 0);
            }
    }
    int drb = (l >> 4) * 4;
    #pragma unroll
    for (int mt = 0; mt < 4; ++mt)
        #pragma unroll
        for (int nt = 0; nt < 4; ++nt)
            #pragma unroll
            for (int e = 0; e < 4; ++e) {
                int row = m0 + wr * 64 + mt * 16 + drb + e;
                int cc  = n0 + wc * 64 + nt * 16 + (l & 15);
                float v = acc[mt][nt][e];
                if (Wadd) v = fmaf(af[row], Wadd[(long)row * N + cc], v);
                C[(long)row * N + cc] = v;
            }
}

// ---------------- fp64 re-check of near-zero dots (sign safety) --------------------
__global__ __launch_bounds__(256) void k_fixup(const unsigned short* __restrict__ Hh,
        const float* __restrict__ w, float* __restrict__ dots) {
    long i = (long)blockIdx.x * 256 + threadIdx.x;
    float d = dots[i];
    if (fabsf(d) < 1e-3f) {
        int s = (int)(i / CA3C), c = (int)(i % CA3C);
        const unsigned short* hr = Hh + (long)s * NN;
        const float* wr = w + (long)c * NN;
        double acc = 0.0;
        for (int n = 0; n < NN; ++n) acc += (double)bf2f(hr[n]) * (double)wr[n];
        dots[i] = (acc > 0.0) ? 1.0f : -1.0f;   // only the sign is consumed
    }
}

// ---------------- pack: preT[w][s] bits, popf[s], dense Xb bf16 (0/1 exact) --------
__global__ __launch_bounds__(64) void k_pack(const float* __restrict__ dots,
        unsigned* __restrict__ preT, float* __restrict__ popf,
        unsigned short* __restrict__ Xb) {
    int s = blockIdx.x;
    int w = threadIdx.x;
    const float* row = dots + (long)s * CA3C + w * 32;
    unsigned short* xrow = Xb + (long)s * CA3C + w * 32;
    unsigned m = 0;
    #pragma unroll
    for (int j4 = 0; j4 < 8; ++j4) {
        f32x4 v = *(const f32x4*)(row + j4 * 4);
        u16x4 xb;
        xb.x = v.x > 0.f ? 0x3F80 : 0; xb.y = v.y > 0.f ? 0x3F80 : 0;
        xb.z = v.z > 0.f ? 0x3F80 : 0; xb.w = v.w > 0.f ? 0x3F80 : 0;
        m |= (v.x > 0.f ? 1u : 0u) << (j4 * 4 + 0);
        m |= (v.y > 0.f ? 1u : 0u) << (j4 * 4 + 1);
        m |= (v.z > 0.f ? 1u : 0u) << (j4 * 4 + 2);
        m |= (v.w > 0.f ? 1u : 0u) << (j4 * 4 + 3);
        *(u16x4*)(xrow + j4 * 4) = xb;
    }
    preT[w * SEQ + s] = m;
    int pc = __popc(m);
    #pragma unroll
    for (int o = 1; o < 64; o <<= 1) pc += __shfl_xor(pc, o, 64);
    if (w == 0) popf[s] = (float)pc;
}

// ---------------- post bits per row: postT[r][32 words over steps 0..1022] ---------
__global__ __launch_bounds__(256) void k_packpost(const float* __restrict__ dots,
        unsigned* __restrict__ postT) {
    int r = blockIdx.x * 256 + threadIdx.x;    // 0..2047
    #pragma unroll 1
    for (int wi = 0; wi < 32; ++wi) {
        unsigned m = 0;
        int jmax = (wi == 31) ? 31 : 32;       // steps s = wi*32+j, s <= 1022
        for (int j = 0; j < jmax; ++j) {
            int s = wi * 32 + j;
            m |= (dots[(long)(s + 1) * CA3C + r] > 0.0f ? 1u : 0u) << j;
        }
        postT[r * 32 + wi] = m;
    }
}

// ---------------- transpose Xb[s][n] -> XbT[n][s] (bf16) ---------------------------
__global__ __launch_bounds__(256) void k_transpose(const unsigned short* __restrict__ Xb,
        unsigned short* __restrict__ XbT) {
    __shared__ unsigned short t[64][72];
    int s0 = blockIdx.x * 64, n0 = blockIdx.y * 64;
    int tx = threadIdx.x & 63, ty = threadIdx.x >> 6;
    #pragma unroll
    for (int ii = 0; ii < 16; ++ii) {
        int i = ty + ii * 4;
        t[i][tx] = Xb[(long)(s0 + i) * CA3C + n0 + tx];
    }
    __syncthreads();
    #pragma unroll
    for (int ii = 0; ii < 16; ++ii) {
        int i = ty + ii * 4;
        XbT[(long)(n0 + i) * SEQ + s0 + tx] = t[tx][i];
    }
}

// ---------------- Gram matrix G[i][j] = x_i . x_j via popcount (fp32 out) ----------
__global__ __launch_bounds__(256) void k_gram(const unsigned* __restrict__ preT,
        float* __restrict__ G) {
    int i = blockIdx.x;
    int t = threadIdx.x;
    int a0 = 0, a1 = 0, a2 = 0, a3 = 0;
    #pragma unroll 8
    for (int w = 0; w < 64; ++w) {
        unsigned ri = preT[w * SEQ + i];       // uniform -> broadcast
        const unsigned* pr = preT + w * SEQ;
        a0 += __popc(ri & pr[t]);
        a1 += __popc(ri & pr[t + 256]);
        a2 += __popc(ri & pr[t + 512]);
        a3 += __popc(ri & pr[t + 768]);
    }
    long base = (long)i * SEQ;
    G[base + t] = (float)a0;       G[base + t + 256] = (float)a1;
    G[base + t + 512] = (float)a2; G[base + t + 768] = (float)a3;
}

// ---------------- DPP-based full-wave (64 lane) sum; broadcast via lane 63 ---------
__device__ __forceinline__ float wave_sum64(float x) {
    #define DPPADD(ctrl, rmask) \
        x += __int_as_float(__builtin_amdgcn_update_dpp(0, __float_as_int(x), ctrl, rmask, 0xF, true))
    DPPADD(0xB1, 0xF);
    DPPADD(0x4E, 0xF);
    DPPADD(0x141, 0xF);
    DPPADD(0x140, 0xF);
    DPPADD(0x142, 0xA);
    DPPADD(0x143, 0xC);
    #undef DPPADD
    return __int_as_float(__builtin_amdgcn_readlane(__float_as_int(x), 63));
}

// ---------------- Phase D (Gram form, left-looking + LDS-staged slab) --------------
// R7 form (coalesced left-looking, 450us) was latency-bound AND 4x-redundant: the
// streamed slab G[s'][64b+lane] is row-independent, so all 4 waves re-read the same
// data via scattered global loads. v3: cooperatively stage the slab in 128-row
// (32 KB) chunks into LDS via global_load_lds, then all waves accumulate from LDS
// (Gs[i][lane]: 64 consecutive floats -> 2-way bank alias = free). Accumulation
// order (mod-4 residue accumulators, ascending s') is BIT-IDENTICAL to R7.
// R9's right-looking form regressed (1070us): per-load wave-uniform branches broke
// load batching -> serialized L2 latency. Reverted.
__global__ __launch_bounds__(256) void k_scan2(const float* __restrict__ W0,
        const float* __restrict__ B0, const float* __restrict__ G,
        const unsigned* __restrict__ postT, const float* __restrict__ popf,
        float* __restrict__ coef, float* __restrict__ alphaf) {
    __shared__ float Gs[128][64];    // 32 KB staged slab chunk
    __shared__ float Gd[64][68];     // diag block (padded)
    __shared__ float ctab[4][1024];  // per-wave c history
    int wid = threadIdx.x >> 6, lane = threadIdx.x & 63;
    int r = blockIdx.x * 4 + wid;
    #pragma unroll
    for (int kk = 0; kk < 16; ++kk) ctab[wid][kk * 64 + lane] = 0.f;
    const float* wr = W0 + (long)r * NN + lane * 32;
    f32x4 q0 = *(const f32x4*)(wr +  0), q1 = *(const f32x4*)(wr +  4);
    f32x4 q2 = *(const f32x4*)(wr +  8), q3 = *(const f32x4*)(wr + 12);
    f32x4 q4 = *(const f32x4*)(wr + 16), q5 = *(const f32x4*)(wr + 20);
    f32x4 q6 = *(const f32x4*)(wr + 24), q7 = *(const f32x4*)(wr + 28);
    f32x4 pp = q0*q0 + q1*q1 + q2*q2 + q3*q3 + q4*q4 + q5*q5 + q6*q6 + q7*q7;
    float nu = wave_sum64((pp.x + pp.y) + (pp.z + pp.w));
    float alpha = 1.f, inv_alpha = 1.f;
    { float t = fmaxf(nu, 1.f); alpha *= rsqrtf(t); inv_alpha *= sqrtf(t); nu = fminf(nu, 1.f); }
    float s0 = 1.f;

    for (int b = 0; b < 16; ++b) {
        __syncthreads();
        {   // cooperative stage of G diag block [64b..64b+63]^2
            int gi = threadIdx.x >> 2, gj = (threadIdx.x & 3) * 16;
            const float* gs = G + (long)(b * 64 + gi) * SEQ + b * 64 + gj;
            *(f32x4*)&Gd[gi][gj +  0] = *(const f32x4*)(gs +  0);
            *(f32x4*)&Gd[gi][gj +  4] = *(const f32x4*)(gs +  4);
            *(f32x4*)&Gd[gi][gj +  8] = *(const f32x4*)(gs +  8);
            *(f32x4*)&Gd[gi][gj + 12] = *(const f32x4*)(gs + 12);
        }
        __syncthreads();
        float myB0  = B0[(long)r * SEQ + b * 64 + lane];
        float mypop = popf[b * 64 + lane];
        unsigned long long pm;
        {   unsigned lo = postT[r * 32 + 2 * b], hi = postT[r * 32 + 2 * b + 1];
            pm = ((unsigned long long)(unsigned)__builtin_amdgcn_readfirstlane((int)hi) << 32)
               |  (unsigned long long)(unsigned)__builtin_amdgcn_readfirstlane((int)lo);
        }
        // inter-block: staged-slab accumulation, chunked 128 s'-rows at a time
        float u0 = 0.f, u1 = 0.f, u2 = 0.f, u3 = 0.f;
        for (int ch = 0; ch < b * 64; ch += 128) {
            int nrows = (b * 64 - ch) < 128 ? (b * 64 - ch) : 128;
            __syncthreads();                 // all waves done reading previous chunk
            for (int t = wid; t < (nrows >> 2); t += 4) {
                // inst t stages G rows ch+4t..ch+4t+3, cols 64b..64b+63 -> Gs[4t..4t+3]
                const float* gsrc = G + (long)(ch + t * 4 + (lane >> 4)) * SEQ
                                      + b * 64 + (lane & 15) * 4;
                __builtin_amdgcn_global_load_lds(
                    (const __attribute__((address_space(1))) unsigned int*)gsrc,
                    (__attribute__((address_space(3))) unsigned int*)&Gs[t * 4][0],
                    16, 0, 0);
            }
            __syncthreads();                 // staging landed (vmcnt drained at barrier)
            #pragma unroll 4
            for (int i = 0; i < nrows; i += 4) {
                f32x4 cq = *(const f32x4*)&ctab[wid][ch + i];   // uniform -> broadcast
                u0 = fmaf(cq.x, Gs[i + 0][lane], u0);
                u1 = fmaf(cq.y, Gs[i + 1][lane], u1);
                u2 = fmaf(cq.z, Gs[i + 2][lane], u2);
                u3 = fmaf(cq.w, Gs[i + 3][lane], u3);
            }
        }
        float acc = fmaf(s0, myB0, (u0 + u1) + (u2 + u3));
        float cj = 0.f;
        #pragma unroll
        for (int j = 0; j < 64; ++j) {
            if ((pm >> j) & 1ull) {          // wave-uniform branch
                float dot = __int_as_float(__builtin_amdgcn_readlane(__float_as_int(acc), j));
                float pj  = __int_as_float(__builtin_amdgcn_readlane(__float_as_int(mypop), j));
                float c = LRC * inv_alpha;
                nu = fmaf(2.f * LRC, alpha * dot, fmaf(LRC * LRC, pj, nu));
                float t = fmaxf(nu, 1.f);
                alpha *= rsqrtf(t); inv_alpha *= sqrtf(t); nu = fminf(nu, 1.f);
                acc = fmaf(c, Gd[j][lane], acc);     // fold step j into future steps
                cj = (lane == j) ? c : cj;
            }
        }
        ctab[wid][b * 64 + lane] = cj;
        if (inv_alpha > 1e10f) {             // rescale event: fold alpha into V-space
            #pragma unroll 1
            for (int kk = 0; kk <= b; ++kk) ctab[wid][kk * 64 + lane] *= alpha;
            s0 *= alpha; alpha = 1.f; inv_alpha = 1.f;
        }
    }
    if (lane == 0) alphaf[r] = alpha * s0;
    #pragma unroll
    for (int kk = 0; kk < 16; ++kk)
        coef[(long)r * SEQ + kk * 64 + lane] = alpha * ctab[wid][kk * 64 + lane];
}

extern "C" void kernel_launch(void* const* d_in, const int* in_sizes, int n_in,
                              void* d_out, int out_size, void* d_ws, size_t ws_size,
                              hipStream_t stream) {
    const int*   tok     = (const int*)d_in[0];
    const float* sdr     = (const float*)d_in[1];
    const float* pos     = (const float*)d_in[2];
    const float* w_hippo = (const float*)d_in[3];
    const float* assoc   = (const float*)d_in[4];
    float* out = (float*)d_out;

    char* ws = (char*)d_ws;
    // Slot map (36.6 MB total, aliased by lifetime):
    unsigned short* Hh  = (unsigned short*)(ws);                 // 0-4 MB (dead after fixup)
    float*          G   = (float*)(ws);                          //   then G (gram, 4 MB)
    unsigned short* Wh  = (unsigned short*)(ws + (4l << 20));    // 4-12 MB (dead after dots)
    unsigned short* Sh  = Wh;                                    //   then assoc-bf16
    unsigned short* Ch  = Wh;                                    //   then coef-hi (4 MB)
    unsigned short* Cl  = (unsigned short*)(ws + (8l << 20));    //   coef-lo   (4 MB)
    unsigned short* Wl  = (unsigned short*)(ws + (12l << 20));   // 12-20 MB (dead after dots)
    float*          coef= (float*)(ws + (12l << 20));            //   then coef fp32 (8 MB)
    float*          dots= (float*)(ws + (20l << 20));            // 20-28 MB (dead after pack)
    float*          B0f = dots;                                  //   then B0 (8 MB)
    unsigned short* Xb  = (unsigned short*)(ws + (28l << 20));   // 28-32 MB
    unsigned short* XbT = (unsigned short*)(ws + (32l << 20));   // 32-36 MB
    unsigned* preT   = (unsigned*)(ws + (36l << 20));            // 256 KB
    unsigned* postT  = (unsigned*)(ws + (36l << 20) + 262144);   // 256 KB
    float*    popf   = (float*)(ws + (36l << 20) + 524288);      // 4 KB
    float*    alphaf = (float*)(ws + (36l << 20) + 532480);      // 8 KB

    k_hippo            <<<dim3(SEQ, 2),   256, 0, stream>>>(tok, sdr, pos, Hh);
    k_split            <<<2048,           256, 0, stream>>>(w_hippo, Wh, Wl);
    k_mgemm<SPLIT_B>   <<<dim3(16, 8),    256, 0, stream>>>(Hh, nullptr, Wh, Wl, dots,
                                                            1024, 2048, 2048, nullptr, nullptr);
    k_fixup            <<<8192,           256, 0, stream>>>(Hh, w_hippo, dots);
    k_pack             <<<SEQ,             64, 0, stream>>>(dots, preT, popf, Xb);
    k_packpost         <<<8,              256, 0, stream>>>(dots, postT);
    k_transpose        <<<dim3(16, 32),   256, 0, stream>>>(Xb, XbT);
    k_gram             <<<SEQ,            256, 0, stream>>>(preT, G);
    k_split            <<<2048,           256, 0, stream>>>(assoc, Sh, nullptr);
    k_mgemm<SPLIT_NONE><<<dim3(8, 16),    256, 0, stream>>>(Sh, nullptr, Xb, nullptr, B0f,
                                                            2048, 1024, 2048, nullptr, nullptr);
    k_scan2            <<<512,            256, 0, stream>>>(assoc, B0f, G, postT, popf, coef, alphaf);
    k_split            <<<1024,           256, 0, stream>>>(coef, Ch, Cl);
    k_mgemm<SPLIT_A>   <<<dim3(16, 16),   256, 0, stream>>>(Ch, Cl, XbT, nullptr, out,
                                                            2048, 2048, 1024, assoc, alphaf);
}

// Round 12
// 826.730 us; speedup vs baseline: 2.0782x; 1.1233x over previous
//
#include <hip/hip_runtime.h>
#include <hip/hip_bf16.h>

#define NT    10
#define NN    2048   // n_neurons
#define CA3C  2048
#define SEQ   1024
#define SPARS 0.05f
#define LRC   0.01f

typedef float          f32x4  __attribute__((ext_vector_type(4)));
typedef short          bf16x8 __attribute__((ext_vector_type(8)));
typedef unsigned short u16x4  __attribute__((ext_vector_type(4)));
typedef unsigned short u16x8  __attribute__((ext_vector_type(8)));

__device__ __forceinline__ unsigned short f2bf(float f) {   // RNE float->bf16 bits
    unsigned u = __float_as_uint(f);
    u += 0x7FFFu + ((u >> 16) & 1u);
    return (unsigned short)(u >> 16);
}
__device__ __forceinline__ float bf2f(unsigned short h) {
    return __uint_as_float(((unsigned)h) << 16);
}

// ---------------- Phase A: hippo_input (exact in bf16: values k*0.5, k<=30) --------
__global__ __launch_bounds__(256) void k_hippo(const int* __restrict__ tok,
        const float* __restrict__ sdr, const float* __restrict__ pos,
        unsigned short* __restrict__ Hh) {
    int s = blockIdx.x;
    int n = (blockIdx.y * 256 + threadIdx.x) * 4;
    const float* sp = sdr + (long)tok[s] * (NT * NN) + n;
    const float* pp = pos + (long)s * (NT * NN) + n;
    float a0 = 0.f, a1 = 0.f, a2 = 0.f, a3 = 0.f;
    #pragma unroll
    for (int t = 0; t < NT; ++t) {
        float4 sv = *(const float4*)(sp + t * NN);
        float4 pv = *(const float4*)(pp + t * NN);
        if (sv.x < SPARS) a0 += (pv.x < SPARS) ? 1.5f : 1.0f;
        if (sv.y < SPARS) a1 += (pv.y < SPARS) ? 1.5f : 1.0f;
        if (sv.z < SPARS) a2 += (pv.z < SPARS) ? 1.5f : 1.0f;
        if (sv.w < SPARS) a3 += (pv.w < SPARS) ? 1.5f : 1.0f;
    }
    u16x4 o = { f2bf(a0), f2bf(a1), f2bf(a2), f2bf(a3) };
    *(u16x4*)(Hh + (long)s * NN + n) = o;
}

// ---------------- split fp32 -> bf16 hi (+ optional lo residual) -------------------
__global__ __launch_bounds__(256) void k_split(const float* __restrict__ src,
        unsigned short* __restrict__ hi, unsigned short* __restrict__ lo) {
    long i = ((long)blockIdx.x * 256 + threadIdx.x) * 8;
    f32x4 x0 = *(const f32x4*)(src + i);
    f32x4 x1 = *(const f32x4*)(src + i + 4);
    float xs[8] = {x0.x, x0.y, x0.z, x0.w, x1.x, x1.y, x1.z, x1.w};
    u16x8 h, l;
    #pragma unroll
    for (int j = 0; j < 8; ++j) {
        unsigned short hb = f2bf(xs[j]);
        h[j] = hb;
        l[j] = f2bf(xs[j] - bf2f(hb));
    }
    *(u16x8*)(hi + i) = h;
    if (lo) *(u16x8*)(lo + i) = l;
}

// ---------------- MFMA GEMM v2: C[M][N] = A @ B^T, bf16 in, fp32 accum -------------
// R11 fix: staging was a 64-row gather per global_load_lds instr (64 cache lines,
// TA line-request bound -- same bug as R6's scan2). v2: BK=64 so each row chunk is
// 128B contiguous; wave reads 8 rows x 128B (~8-16 lines/instr, 8x fewer); regs ->
// ds_write_b128 into LDS rows padded to 70 shorts (write & read <=2-way bank alias).
// Next tile's global loads issue BEFORE the MFMA block (latency hides under MFMA).
// MFMA order per accumulator identical to R8-R11 -> bit-identical C.
#define SPLIT_NONE 0
#define SPLIT_A    1
#define SPLIT_B    2

template<int MODE>
__global__ __launch_bounds__(256, 1) void k_mgemm(
        const unsigned short* __restrict__ A0, const unsigned short* __restrict__ A1,
        const unsigned short* __restrict__ Bh, const unsigned short* __restrict__ B1,
        float* __restrict__ C, int M, int N, int K,
        const float* __restrict__ Wadd, const float* __restrict__ af) {
    __shared__ unsigned short LA[128 * 70], LB[128 * 70], LX[128 * 70];   // 17.9 KB each
    int tid = threadIdx.x, wid = tid >> 6, l = tid & 63;
    int m0 = blockIdx.y * 128, n0 = blockIdx.x * 128;
    int wr = wid >> 1, wc = wid & 1;
    int fr = l & 15, fk = l >> 4;
    f32x4 acc[4][4] = {};
    int srow = wid * 8 + (l >> 3);          // + i*32 -> rows 0..127
    int scol = (l & 7) * 8;                 // 16B chunk within 64-short row segment
    bf16x8 ra[4], rb[4], rx[4];
    #pragma unroll
    for (int i = 0; i < 4; ++i) {           // prefetch k-tile 0
        int row = i * 32 + srow;
        ra[i] = *(const bf16x8*)(A0 + (long)(m0 + row) * K + scol);
        rb[i] = *(const bf16x8*)(Bh + (long)(n0 + row) * K + scol);
        if (MODE == SPLIT_A) rx[i] = *(const bf16x8*)(A1 + (long)(m0 + row) * K + scol);
        if (MODE == SPLIT_B) rx[i] = *(const bf16x8*)(B1 + (long)(n0 + row) * K + scol);
    }
    for (int k0 = 0; k0 < K; k0 += 64) {
        __syncthreads();                    // prior tile's LDS reads done
        #pragma unroll
        for (int i = 0; i < 4; ++i) {
            int row = i * 32 + srow;
            *(bf16x8*)&LA[row * 70 + scol] = ra[i];
            *(bf16x8*)&LB[row * 70 + scol] = rb[i];
            if (MODE != SPLIT_NONE) *(bf16x8*)&LX[row * 70 + scol] = rx[i];
        }
        __syncthreads();                    // tile visible
        if (k0 + 64 < K) {                  // issue next tile's loads (hide under MFMA)
            #pragma unroll
            for (int i = 0; i < 4; ++i) {
                int row = i * 32 + srow;
                ra[i] = *(const bf16x8*)(A0 + (long)(m0 + row) * K + k0 + 64 + scol);
                rb[i] = *(const bf16x8*)(Bh + (long)(n0 + row) * K + k0 + 64 + scol);
                if (MODE == SPLIT_A) rx[i] = *(const bf16x8*)(A1 + (long)(m0 + row) * K + k0 + 64 + scol);
                if (MODE == SPLIT_B) rx[i] = *(const bf16x8*)(B1 + (long)(n0 + row) * K + k0 + 64 + scol);
            }
        }
        #pragma unroll
        for (int ks = 0; ks < 2; ++ks) {
            bf16x8 av[4], bv[4], xv[4];
            #pragma unroll
            for (int t = 0; t < 4; ++t) {
                av[t] = *(const bf16x8*)&LA[(wr * 64 + t * 16 + fr) * 70 + ks * 32 + fk * 8];
                bv[t] = *(const bf16x8*)&LB[(wc * 64 + t * 16 + fr) * 70 + ks * 32 + fk * 8];
                if (MODE == SPLIT_A) xv[t] = *(const bf16x8*)&LX[(wr * 64 + t * 16 + fr) * 70 + ks * 32 + fk * 8];
                if (MODE == SPLIT_B) xv[t] = *(const bf16x8*)&LX[(wc * 64 + t * 16 + fr) * 70 + ks * 32 + fk * 8];
            }
            #pragma unroll
            for (int mt = 0; mt < 4; ++mt)
                #pragma unroll
                for (int nt = 0; nt < 4; ++nt) {
                    acc[mt][nt] = __builtin_amdgcn_mfma_f32_16x16x32_bf16(av[mt], bv[nt], acc[mt][nt], 0, 0, 0);
                    if (MODE == SPLIT_A)
                        acc[mt][nt] = __builtin_amdgcn_mfma_f32_16x16x32_bf16(xv[mt], bv[nt], acc[mt][nt], 0, 0, 0);
                    if (MODE == SPLIT_B)
                        acc[mt][nt] = __builtin_amdgcn_mfma_f32_16x16x32_bf16(av[mt], xv[nt], acc[mt][nt], 0, 0, 0);
                }
        }
    }
    int drb = (l >> 4) * 4;
    #pragma unroll
    for (int mt = 0; mt < 4; ++mt)
        #pragma unroll
        for (int nt = 0; nt < 4; ++nt)
            #pragma unroll
            for (int e = 0; e < 4; ++e) {
                int row = m0 + wr * 64 + mt * 16 + drb + e;
                int cc  = n0 + wc * 64 + nt * 16 + (l & 15);
                float v = acc[mt][nt][e];
                if (Wadd) v = fmaf(af[row], Wadd[(long)row * N + cc], v);
                C[(long)row * N + cc] = v;
            }
}

// ---------------- fp64 re-check of near-zero dots (sign safety) --------------------
__global__ __launch_bounds__(256) void k_fixup(const unsigned short* __restrict__ Hh,
        const float* __restrict__ w, float* __restrict__ dots) {
    long i = (long)blockIdx.x * 256 + threadIdx.x;
    float d = dots[i];
    if (fabsf(d) < 1e-3f) {
        int s = (int)(i / CA3C), c = (int)(i % CA3C);
        const unsigned short* hr = Hh + (long)s * NN;
        const float* wr = w + (long)c * NN;
        double acc = 0.0;
        for (int n = 0; n < NN; ++n) acc += (double)bf2f(hr[n]) * (double)wr[n];
        dots[i] = (acc > 0.0) ? 1.0f : -1.0f;   // only the sign is consumed
    }
}

// ---------------- pack: preT[w][s] bits, popf[s], dense Xb bf16 (0/1 exact) --------
__global__ __launch_bounds__(64) void k_pack(const float* __restrict__ dots,
        unsigned* __restrict__ preT, float* __restrict__ popf,
        unsigned short* __restrict__ Xb) {
    int s = blockIdx.x;
    int w = threadIdx.x;
    const float* row = dots + (long)s * CA3C + w * 32;
    unsigned short* xrow = Xb + (long)s * CA3C + w * 32;
    unsigned m = 0;
    #pragma unroll
    for (int j4 = 0; j4 < 8; ++j4) {
        f32x4 v = *(const f32x4*)(row + j4 * 4);
        u16x4 xb;
        xb.x = v.x > 0.f ? 0x3F80 : 0; xb.y = v.y > 0.f ? 0x3F80 : 0;
        xb.z = v.z > 0.f ? 0x3F80 : 0; xb.w = v.w > 0.f ? 0x3F80 : 0;
        m |= (v.x > 0.f ? 1u : 0u) << (j4 * 4 + 0);
        m |= (v.y > 0.f ? 1u : 0u) << (j4 * 4 + 1);
        m |= (v.z > 0.f ? 1u : 0u) << (j4 * 4 + 2);
        m |= (v.w > 0.f ? 1u : 0u) << (j4 * 4 + 3);
        *(u16x4*)(xrow + j4 * 4) = xb;
    }
    preT[w * SEQ + s] = m;
    int pc = __popc(m);
    #pragma unroll
    for (int o = 1; o < 64; o <<= 1) pc += __shfl_xor(pc, o, 64);
    if (w == 0) popf[s] = (float)pc;
}

// ---------------- post bits per row: postT[r][32 words over steps 0..1022] ---------
__global__ __launch_bounds__(256) void k_packpost(const float* __restrict__ dots,
        unsigned* __restrict__ postT) {
    int r = blockIdx.x * 256 + threadIdx.x;    // 0..2047
    #pragma unroll 1
    for (int wi = 0; wi < 32; ++wi) {
        unsigned m = 0;
        int jmax = (wi == 31) ? 31 : 32;       // steps s = wi*32+j, s <= 1022
        for (int j = 0; j < jmax; ++j) {
            int s = wi * 32 + j;
            m |= (dots[(long)(s + 1) * CA3C + r] > 0.0f ? 1u : 0u) << j;
        }
        postT[r * 32 + wi] = m;
    }
}

// ---------------- transpose Xb[s][n] -> XbT[n][s] (bf16) ---------------------------
__global__ __launch_bounds__(256) void k_transpose(const unsigned short* __restrict__ Xb,
        unsigned short* __restrict__ XbT) {
    __shared__ unsigned short t[64][72];
    int s0 = blockIdx.x * 64, n0 = blockIdx.y * 64;
    int tx = threadIdx.x & 63, ty = threadIdx.x >> 6;
    #pragma unroll
    for (int ii = 0; ii < 16; ++ii) {
        int i = ty + ii * 4;
        t[i][tx] = Xb[(long)(s0 + i) * CA3C + n0 + tx];
    }
    __syncthreads();
    #pragma unroll
    for (int ii = 0; ii < 16; ++ii) {
        int i = ty + ii * 4;
        XbT[(long)(n0 + i) * SEQ + s0 + tx] = t[tx][i];
    }
}

// ---------------- Gram matrix G[i][j] = x_i . x_j via popcount (fp32 out) ----------
__global__ __launch_bounds__(256) void k_gram(const unsigned* __restrict__ preT,
        float* __restrict__ G) {
    int i = blockIdx.x;
    int t = threadIdx.x;
    int a0 = 0, a1 = 0, a2 = 0, a3 = 0;
    #pragma unroll 8
    for (int w = 0; w < 64; ++w) {
        unsigned ri = preT[w * SEQ + i];       // uniform -> broadcast
        const unsigned* pr = preT + w * SEQ;
        a0 += __popc(ri & pr[t]);
        a1 += __popc(ri & pr[t + 256]);
        a2 += __popc(ri & pr[t + 512]);
        a3 += __popc(ri & pr[t + 768]);
    }
    long base = (long)i * SEQ;
    G[base + t] = (float)a0;       G[base + t + 256] = (float)a1;
    G[base + t + 512] = (float)a2; G[base + t + 768] = (float)a3;
}

// ---------------- DPP-based full-wave (64 lane) sum; broadcast via lane 63 ---------
__device__ __forceinline__ float wave_sum64(float x) {
    #define DPPADD(ctrl, rmask) \
        x += __int_as_float(__builtin_amdgcn_update_dpp(0, __float_as_int(x), ctrl, rmask, 0xF, true))
    DPPADD(0xB1, 0xF);
    DPPADD(0x4E, 0xF);
    DPPADD(0x141, 0xF);
    DPPADD(0x140, 0xF);
    DPPADD(0x142, 0xA);
    DPPADD(0x143, 0xC);
    #undef DPPADD
    return __int_as_float(__builtin_amdgcn_readlane(__float_as_int(x), 63));
}

// ---------------- Phase D (Gram form, left-looking + LDS-staged slab) --------------
// Unchanged from R11 (454 -> <390us): slab G[s'][64b+lane] staged in 128-row chunks
// via global_load_lds (lane-linear dest), all 4 waves accumulate from LDS.
__global__ __launch_bounds__(256) void k_scan2(const float* __restrict__ W0,
        const float* __restrict__ B0, const float* __restrict__ G,
        const unsigned* __restrict__ postT, const float* __restrict__ popf,
        float* __restrict__ coef, float* __restrict__ alphaf) {
    __shared__ float Gs[128][64];    // 32 KB staged slab chunk
    __shared__ float Gd[64][68];     // diag block (padded)
    __shared__ float ctab[4][1024];  // per-wave c history
    int wid = threadIdx.x >> 6, lane = threadIdx.x & 63;
    int r = blockIdx.x * 4 + wid;
    #pragma unroll
    for (int kk = 0; kk < 16; ++kk) ctab[wid][kk * 64 + lane] = 0.f;
    const float* wr = W0 + (long)r * NN + lane * 32;
    f32x4 q0 = *(const f32x4*)(wr +  0), q1 = *(const f32x4*)(wr +  4);
    f32x4 q2 = *(const f32x4*)(wr +  8), q3 = *(const f32x4*)(wr + 12);
    f32x4 q4 = *(const f32x4*)(wr + 16), q5 = *(const f32x4*)(wr + 20);
    f32x4 q6 = *(const f32x4*)(wr + 24), q7 = *(const f32x4*)(wr + 28);
    f32x4 pp = q0*q0 + q1*q1 + q2*q2 + q3*q3 + q4*q4 + q5*q5 + q6*q6 + q7*q7;
    float nu = wave_sum64((pp.x + pp.y) + (pp.z + pp.w));
    float alpha = 1.f, inv_alpha = 1.f;
    { float t = fmaxf(nu, 1.f); alpha *= rsqrtf(t); inv_alpha *= sqrtf(t); nu = fminf(nu, 1.f); }
    float s0 = 1.f;

    for (int b = 0; b < 16; ++b) {
        __syncthreads();
        {   // cooperative stage of G diag block [64b..64b+63]^2
            int gi = threadIdx.x >> 2, gj = (threadIdx.x & 3) * 16;
            const float* gs = G + (long)(b * 64 + gi) * SEQ + b * 64 + gj;
            *(f32x4*)&Gd[gi][gj +  0] = *(const f32x4*)(gs +  0);
            *(f32x4*)&Gd[gi][gj +  4] = *(const f32x4*)(gs +  4);
            *(f32x4*)&Gd[gi][gj +  8] = *(const f32x4*)(gs +  8);
            *(f32x4*)&Gd[gi][gj + 12] = *(const f32x4*)(gs + 12);
        }
        __syncthreads();
        float myB0  = B0[(long)r * SEQ + b * 64 + lane];
        float mypop = popf[b * 64 + lane];
        unsigned long long pm;
        {   unsigned lo = postT[r * 32 + 2 * b], hi = postT[r * 32 + 2 * b + 1];
            pm = ((unsigned long long)(unsigned)__builtin_amdgcn_readfirstlane((int)hi) << 32)
               |  (unsigned long long)(unsigned)__builtin_amdgcn_readfirstlane((int)lo);
        }
        // inter-block: staged-slab accumulation, chunked 128 s'-rows at a time
        float u0 = 0.f, u1 = 0.f, u2 = 0.f, u3 = 0.f;
        for (int ch = 0; ch < b * 64; ch += 128) {
            int nrows = (b * 64 - ch) < 128 ? (b * 64 - ch) : 128;
            __syncthreads();                 // all waves done reading previous chunk
            for (int t = wid; t < (nrows >> 2); t += 4) {
                const float* gsrc = G + (long)(ch + t * 4 + (lane >> 4)) * SEQ
                                      + b * 64 + (lane & 15) * 4;
                __builtin_amdgcn_global_load_lds(
                    (const __attribute__((address_space(1))) unsigned int*)gsrc,
                    (__attribute__((address_space(3))) unsigned int*)&Gs[t * 4][0],
                    16, 0, 0);
            }
            __syncthreads();                 // staging landed
            #pragma unroll 4
            for (int i = 0; i < nrows; i += 4) {
                f32x4 cq = *(const f32x4*)&ctab[wid][ch + i];   // uniform -> broadcast
                u0 = fmaf(cq.x, Gs[i + 0][lane], u0);
                u1 = fmaf(cq.y, Gs[i + 1][lane], u1);
                u2 = fmaf(cq.z, Gs[i + 2][lane], u2);
                u3 = fmaf(cq.w, Gs[i + 3][lane], u3);
            }
        }
        float acc = fmaf(s0, myB0, (u0 + u1) + (u2 + u3));
        float cj = 0.f;
        #pragma unroll
        for (int j = 0; j < 64; ++j) {
            if ((pm >> j) & 1ull) {          // wave-uniform branch
                float dot = __int_as_float(__builtin_amdgcn_readlane(__float_as_int(acc), j));
                float pj  = __int_as_float(__builtin_amdgcn_readlane(__float_as_int(mypop), j));
                float c = LRC * inv_alpha;
                nu = fmaf(2.f * LRC, alpha * dot, fmaf(LRC * LRC, pj, nu));
                float t = fmaxf(nu, 1.f);
                alpha *= rsqrtf(t); inv_alpha *= sqrtf(t); nu = fminf(nu, 1.f);
                acc = fmaf(c, Gd[j][lane], acc);     // fold step j into future steps
                cj = (lane == j) ? c : cj;
            }
        }
        ctab[wid][b * 64 + lane] = cj;
        if (inv_alpha > 1e10f) {             // rescale event: fold alpha into V-space
            #pragma unroll 1
            for (int kk = 0; kk <= b; ++kk) ctab[wid][kk * 64 + lane] *= alpha;
            s0 *= alpha; alpha = 1.f; inv_alpha = 1.f;
        }
    }
    if (lane == 0) alphaf[r] = alpha * s0;
    #pragma unroll
    for (int kk = 0; kk < 16; ++kk)
        coef[(long)r * SEQ + kk * 64 + lane] = alpha * ctab[wid][kk * 64 + lane];
}

extern "C" void kernel_launch(void* const* d_in, const int* in_sizes, int n_in,
                              void* d_out, int out_size, void* d_ws, size_t ws_size,
                              hipStream_t stream) {
    const int*   tok     = (const int*)d_in[0];
    const float* sdr     = (const float*)d_in[1];
    const float* pos     = (const float*)d_in[2];
    const float* w_hippo = (const float*)d_in[3];
    const float* assoc   = (const float*)d_in[4];
    float* out = (float*)d_out;

    char* ws = (char*)d_ws;
    // Slot map (36.6 MB total, aliased by lifetime):
    unsigned short* Hh  = (unsigned short*)(ws);                 // 0-4 MB (dead after fixup)
    float*          G   = (float*)(ws);                          //   then G (gram, 4 MB)
    unsigned short* Wh  = (unsigned short*)(ws + (4l << 20));    // 4-12 MB (dead after dots)
    unsigned short* Sh  = Wh;                                    //   then assoc-bf16
    unsigned short* Ch  = Wh;                                    //   then coef-hi (4 MB)
    unsigned short* Cl  = (unsigned short*)(ws + (8l << 20));    //   coef-lo   (4 MB)
    unsigned short* Wl  = (unsigned short*)(ws + (12l << 20));   // 12-20 MB (dead after dots)
    float*          coef= (float*)(ws + (12l << 20));            //   then coef fp32 (8 MB)
    float*          dots= (float*)(ws + (20l << 20));            // 20-28 MB (dead after pack)
    float*          B0f = dots;                                  //   then B0 (8 MB)
    unsigned short* Xb  = (unsigned short*)(ws + (28l << 20));   // 28-32 MB
    unsigned short* XbT = (unsigned short*)(ws + (32l << 20));   // 32-36 MB
    unsigned* preT   = (unsigned*)(ws + (36l << 20));            // 256 KB
    unsigned* postT  = (unsigned*)(ws + (36l << 20) + 262144);   // 256 KB
    float*    popf   = (float*)(ws + (36l << 20) + 524288);      // 4 KB
    float*    alphaf = (float*)(ws + (36l << 20) + 532480);      // 8 KB

    k_hippo            <<<dim3(SEQ, 2),   256, 0, stream>>>(tok, sdr, pos, Hh);
    k_split            <<<2048,           256, 0, stream>>>(w_hippo, Wh, Wl);
    k_mgemm<SPLIT_B>   <<<dim3(16, 8),    256, 0, stream>>>(Hh, nullptr, Wh, Wl, dots,
                                                            1024, 2048, 2048, nullptr, nullptr);
    k_fixup            <<<8192,           256, 0, stream>>>(Hh, w_hippo, dots);
    k_pack             <<<SEQ,             64, 0, stream>>>(dots, preT, popf, Xb);
    k_packpost         <<<8,              256, 0, stream>>>(dots, postT);
    k_transpose        <<<dim3(16, 32),   256, 0, stream>>>(Xb, XbT);
    k_gram             <<<SEQ,            256, 0, stream>>>(preT, G);
    k_split            <<<2048,           256, 0, stream>>>(assoc, Sh, nullptr);
    k_mgemm<SPLIT_NONE><<<dim3(8, 16),    256, 0, stream>>>(Sh, nullptr, Xb, nullptr, B0f,
                                                            2048, 1024, 2048, nullptr, nullptr);
    k_scan2            <<<512,            256, 0, stream>>>(assoc, B0f, G, postT, popf, coef, alphaf);
    k_split            <<<1024,           256, 0, stream>>>(coef, Ch, Cl);
    k_mgemm<SPLIT_A>   <<<dim3(16, 16),   256, 0, stream>>>(Ch, Cl, XbT, nullptr, out,
                                                            2048, 2048, 1024, assoc, alphaf);
}

// Round 13
// 684.582 us; speedup vs baseline: 2.5097x; 1.2076x over previous
//
#include <hip/hip_runtime.h>
#include <hip/hip_bf16.h>

#define NT    10
#define NN    2048   // n_neurons
#define CA3C  2048
#define SEQ   1024
#define SPARS 0.05f
#define LRC   0.01f

typedef float          f32x4  __attribute__((ext_vector_type(4)));
typedef short          bf16x8 __attribute__((ext_vector_type(8)));
typedef unsigned short u16x4  __attribute__((ext_vector_type(4)));
typedef unsigned short u16x8  __attribute__((ext_vector_type(8)));

__device__ __forceinline__ unsigned short f2bf(float f) {   // RNE float->bf16 bits
    unsigned u = __float_as_uint(f);
    u += 0x7FFFu + ((u >> 16) & 1u);
    return (unsigned short)(u >> 16);
}
__device__ __forceinline__ float bf2f(unsigned short h) {
    return __uint_as_float(((unsigned)h) << 16);
}

// ---------------- Phase A: hippo_input (exact in bf16: values k*0.5, k<=30) --------
__global__ __launch_bounds__(256) void k_hippo(const int* __restrict__ tok,
        const float* __restrict__ sdr, const float* __restrict__ pos,
        unsigned short* __restrict__ Hh) {
    int s = blockIdx.x;
    int n = (blockIdx.y * 256 + threadIdx.x) * 4;
    const float* sp = sdr + (long)tok[s] * (NT * NN) + n;
    const float* pp = pos + (long)s * (NT * NN) + n;
    float a0 = 0.f, a1 = 0.f, a2 = 0.f, a3 = 0.f;
    #pragma unroll
    for (int t = 0; t < NT; ++t) {
        float4 sv = *(const float4*)(sp + t * NN);
        float4 pv = *(const float4*)(pp + t * NN);
        if (sv.x < SPARS) a0 += (pv.x < SPARS) ? 1.5f : 1.0f;
        if (sv.y < SPARS) a1 += (pv.y < SPARS) ? 1.5f : 1.0f;
        if (sv.z < SPARS) a2 += (pv.z < SPARS) ? 1.5f : 1.0f;
        if (sv.w < SPARS) a3 += (pv.w < SPARS) ? 1.5f : 1.0f;
    }
    u16x4 o = { f2bf(a0), f2bf(a1), f2bf(a2), f2bf(a3) };
    *(u16x4*)(Hh + (long)s * NN + n) = o;
}

// ---------------- split fp32 -> bf16 hi (+ optional lo residual) -------------------
__global__ __launch_bounds__(256) void k_split(const float* __restrict__ src,
        unsigned short* __restrict__ hi, unsigned short* __restrict__ lo) {
    long i = ((long)blockIdx.x * 256 + threadIdx.x) * 8;
    f32x4 x0 = *(const f32x4*)(src + i);
    f32x4 x1 = *(const f32x4*)(src + i + 4);
    float xs[8] = {x0.x, x0.y, x0.z, x0.w, x1.x, x1.y, x1.z, x1.w};
    u16x8 h, l;
    #pragma unroll
    for (int j = 0; j < 8; ++j) {
        unsigned short hb = f2bf(xs[j]);
        h[j] = hb;
        l[j] = f2bf(xs[j] - bf2f(hb));
    }
    *(u16x8*)(hi + i) = h;
    if (lo) *(u16x8*)(lo + i) = l;
}

// ---------------- MFMA GEMM v2 (unchanged from R12): C = A @ B^T -------------------
#define SPLIT_NONE 0
#define SPLIT_A    1
#define SPLIT_B    2

template<int MODE>
__global__ __launch_bounds__(256, 1) void k_mgemm(
        const unsigned short* __restrict__ A0, const unsigned short* __restrict__ A1,
        const unsigned short* __restrict__ Bh, const unsigned short* __restrict__ B1,
        float* __restrict__ C, int M, int N, int K,
        const float* __restrict__ Wadd, const float* __restrict__ af) {
    __shared__ unsigned short LA[128 * 70], LB[128 * 70], LX[128 * 70];   // 17.9 KB each
    int tid = threadIdx.x, wid = tid >> 6, l = tid & 63;
    int m0 = blockIdx.y * 128, n0 = blockIdx.x * 128;
    int wr = wid >> 1, wc = wid & 1;
    int fr = l & 15, fk = l >> 4;
    f32x4 acc[4][4] = {};
    int srow = wid * 8 + (l >> 3);          // + i*32 -> rows 0..127
    int scol = (l & 7) * 8;                 // 16B chunk within 64-short row segment
    bf16x8 ra[4], rb[4], rx[4];
    #pragma unroll
    for (int i = 0; i < 4; ++i) {           // prefetch k-tile 0
        int row = i * 32 + srow;
        ra[i] = *(const bf16x8*)(A0 + (long)(m0 + row) * K + scol);
        rb[i] = *(const bf16x8*)(Bh + (long)(n0 + row) * K + scol);
        if (MODE == SPLIT_A) rx[i] = *(const bf16x8*)(A1 + (long)(m0 + row) * K + scol);
        if (MODE == SPLIT_B) rx[i] = *(const bf16x8*)(B1 + (long)(n0 + row) * K + scol);
    }
    for (int k0 = 0; k0 < K; k0 += 64) {
        __syncthreads();                    // prior tile's LDS reads done
        #pragma unroll
        for (int i = 0; i < 4; ++i) {
            int row = i * 32 + srow;
            *(bf16x8*)&LA[row * 70 + scol] = ra[i];
            *(bf16x8*)&LB[row * 70 + scol] = rb[i];
            if (MODE != SPLIT_NONE) *(bf16x8*)&LX[row * 70 + scol] = rx[i];
        }
        __syncthreads();                    // tile visible
        if (k0 + 64 < K) {                  // issue next tile's loads (hide under MFMA)
            #pragma unroll
            for (int i = 0; i < 4; ++i) {
                int row = i * 32 + srow;
                ra[i] = *(const bf16x8*)(A0 + (long)(m0 + row) * K + k0 + 64 + scol);
                rb[i] = *(const bf16x8*)(Bh + (long)(n0 + row) * K + k0 + 64 + scol);
                if (MODE == SPLIT_A) rx[i] = *(const bf16x8*)(A1 + (long)(m0 + row) * K + k0 + 64 + scol);
                if (MODE == SPLIT_B) rx[i] = *(const bf16x8*)(B1 + (long)(n0 + row) * K + k0 + 64 + scol);
            }
        }
        #pragma unroll
        for (int ks = 0; ks < 2; ++ks) {
            bf16x8 av[4], bv[4], xv[4];
            #pragma unroll
            for (int t = 0; t < 4; ++t) {
                av[t] = *(const bf16x8*)&LA[(wr * 64 + t * 16 + fr) * 70 + ks * 32 + fk * 8];
                bv[t] = *(const bf16x8*)&LB[(wc * 64 + t * 16 + fr) * 70 + ks * 32 + fk * 8];
                if (MODE == SPLIT_A) xv[t] = *(const bf16x8*)&LX[(wr * 64 + t * 16 + fr) * 70 + ks * 32 + fk * 8];
                if (MODE == SPLIT_B) xv[t] = *(const bf16x8*)&LX[(wc * 64 + t * 16 + fr) * 70 + ks * 32 + fk * 8];
            }
            #pragma unroll
            for (int mt = 0; mt < 4; ++mt)
                #pragma unroll
                for (int nt = 0; nt < 4; ++nt) {
                    acc[mt][nt] = __builtin_amdgcn_mfma_f32_16x16x32_bf16(av[mt], bv[nt], acc[mt][nt], 0, 0, 0);
                    if (MODE == SPLIT_A)
                        acc[mt][nt] = __builtin_amdgcn_mfma_f32_16x16x32_bf16(xv[mt], bv[nt], acc[mt][nt], 0, 0, 0);
                    if (MODE == SPLIT_B)
                        acc[mt][nt] = __builtin_amdgcn_mfma_f32_16x16x32_bf16(av[mt], xv[nt], acc[mt][nt], 0, 0, 0);
                }
        }
    }
    int drb = (l >> 4) * 4;
    #pragma unroll
    for (int mt = 0; mt < 4; ++mt)
        #pragma unroll
        for (int nt = 0; nt < 4; ++nt)
            #pragma unroll
            for (int e = 0; e < 4; ++e) {
                int row = m0 + wr * 64 + mt * 16 + drb + e;
                int cc  = n0 + wc * 64 + nt * 16 + (l & 15);
                float v = acc[mt][nt][e];
                if (Wadd) v = fmaf(af[row], Wadd[(long)row * N + cc], v);
                C[(long)row * N + cc] = v;
            }
}

// ---------------- fp64 re-check of near-zero dots (sign safety) --------------------
__global__ __launch_bounds__(256) void k_fixup(const unsigned short* __restrict__ Hh,
        const float* __restrict__ w, float* __restrict__ dots) {
    long i = (long)blockIdx.x * 256 + threadIdx.x;
    float d = dots[i];
    if (fabsf(d) < 1e-3f) {
        int s = (int)(i / CA3C), c = (int)(i % CA3C);
        const unsigned short* hr = Hh + (long)s * NN;
        const float* wr = w + (long)c * NN;
        double acc = 0.0;
        for (int n = 0; n < NN; ++n) acc += (double)bf2f(hr[n]) * (double)wr[n];
        dots[i] = (acc > 0.0) ? 1.0f : -1.0f;   // only the sign is consumed
    }
}

// ---------------- pack: preT[w][s] bits, popf[s], dense Xb bf16 (0/1 exact) --------
__global__ __launch_bounds__(64) void k_pack(const float* __restrict__ dots,
        unsigned* __restrict__ preT, float* __restrict__ popf,
        unsigned short* __restrict__ Xb) {
    int s = blockIdx.x;
    int w = threadIdx.x;
    const float* row = dots + (long)s * CA3C + w * 32;
    unsigned short* xrow = Xb + (long)s * CA3C + w * 32;
    unsigned m = 0;
    #pragma unroll
    for (int j4 = 0; j4 < 8; ++j4) {
        f32x4 v = *(const f32x4*)(row + j4 * 4);
        u16x4 xb;
        xb.x = v.x > 0.f ? 0x3F80 : 0; xb.y = v.y > 0.f ? 0x3F80 : 0;
        xb.z = v.z > 0.f ? 0x3F80 : 0; xb.w = v.w > 0.f ? 0x3F80 : 0;
        m |= (v.x > 0.f ? 1u : 0u) << (j4 * 4 + 0);
        m |= (v.y > 0.f ? 1u : 0u) << (j4 * 4 + 1);
        m |= (v.z > 0.f ? 1u : 0u) << (j4 * 4 + 2);
        m |= (v.w > 0.f ? 1u : 0u) << (j4 * 4 + 3);
        *(u16x4*)(xrow + j4 * 4) = xb;
    }
    preT[w * SEQ + s] = m;
    int pc = __popc(m);
    #pragma unroll
    for (int o = 1; o < 64; o <<= 1) pc += __shfl_xor(pc, o, 64);
    if (w == 0) popf[s] = (float)pc;
}

// ---------------- post bits v2: ballot-based 64x64 tile transpose ------------------
// R12 form had 8 blocks (32 waves machine-wide), each thread serially issuing 1024
// L2 loads with a runtime-bounded inner loop (no unroll, no TLP -> latency-bound).
// v2: 512 tiles (64 rows x 64 steps); coalesced row-loads + __ballot per step ->
// uint64 masks in LDS -> lane r bit-gathers its row's two 32-bit words.
__global__ __launch_bounds__(256) void k_packpost(const float* __restrict__ dots,
        unsigned* __restrict__ postT) {
    __shared__ unsigned long long masks[4][64];
    int wid = threadIdx.x >> 6, lane = threadIdx.x & 63;
    int tile = blockIdx.x * 4 + wid;           // 0..511
    int rg = tile & 31, sg = tile >> 5;        // row-group 0..31, step-group 0..15
    int r0 = rg * 64;
    #pragma unroll 8
    for (int k = 0; k < 64; ++k) {
        int s = sg * 64 + k;                   // step index; valid steps are 0..1022
        float d = (s < SEQ - 1) ? dots[(long)(s + 1) * CA3C + r0 + lane] : -1.f;
        unsigned long long m = __ballot(d > 0.f);
        if (lane == 0) masks[wid][k] = m;
    }
    unsigned w0 = 0, w1 = 0;
    #pragma unroll
    for (int k = 0; k < 32; ++k) {
        w0 |= (unsigned)((masks[wid][k]      >> lane) & 1ull) << k;
        w1 |= (unsigned)((masks[wid][k + 32] >> lane) & 1ull) << k;
    }
    postT[(r0 + lane) * 32 + sg * 2]     = w0;
    postT[(r0 + lane) * 32 + sg * 2 + 1] = w1;
}

// ---------------- transpose Xb[s][n] -> XbT[n][s] (bf16) ---------------------------
__global__ __launch_bounds__(256) void k_transpose(const unsigned short* __restrict__ Xb,
        unsigned short* __restrict__ XbT) {
    __shared__ unsigned short t[64][72];
    int s0 = blockIdx.x * 64, n0 = blockIdx.y * 64;
    int tx = threadIdx.x & 63, ty = threadIdx.x >> 6;
    #pragma unroll
    for (int ii = 0; ii < 16; ++ii) {
        int i = ty + ii * 4;
        t[i][tx] = Xb[(long)(s0 + i) * CA3C + n0 + tx];
    }
    __syncthreads();
    #pragma unroll
    for (int ii = 0; ii < 16; ++ii) {
        int i = ty + ii * 4;
        XbT[(long)(n0 + i) * SEQ + s0 + tx] = t[tx][i];
    }
}

// ---------------- Gram matrix G[i][j] = x_i . x_j via popcount (fp32 out) ----------
__global__ __launch_bounds__(256) void k_gram(const unsigned* __restrict__ preT,
        float* __restrict__ G) {
    int i = blockIdx.x;
    int t = threadIdx.x;
    int a0 = 0, a1 = 0, a2 = 0, a3 = 0;
    #pragma unroll 8
    for (int w = 0; w < 64; ++w) {
        unsigned ri = preT[w * SEQ + i];       // uniform -> broadcast
        const unsigned* pr = preT + w * SEQ;
        a0 += __popc(ri & pr[t]);
        a1 += __popc(ri & pr[t + 256]);
        a2 += __popc(ri & pr[t + 512]);
        a3 += __popc(ri & pr[t + 768]);
    }
    long base = (long)i * SEQ;
    G[base + t] = (float)a0;       G[base + t + 256] = (float)a1;
    G[base + t + 512] = (float)a2; G[base + t + 768] = (float)a3;
}

// ---------------- DPP-based full-wave (64 lane) sum; broadcast via lane 63 ---------
__device__ __forceinline__ float wave_sum64(float x) {
    #define DPPADD(ctrl, rmask) \
        x += __int_as_float(__builtin_amdgcn_update_dpp(0, __float_as_int(x), ctrl, rmask, 0xF, true))
    DPPADD(0xB1, 0xF);
    DPPADD(0x4E, 0xF);
    DPPADD(0x141, 0xF);
    DPPADD(0x140, 0xF);
    DPPADD(0x142, 0xA);
    DPPADD(0x143, 0xC);
    #undef DPPADD
    return __int_as_float(__builtin_amdgcn_readlane(__float_as_int(x), 63));
}

// ---------------- Phase D v3: left-looking, reg-double-buffered 64-row chunks ------
// R12 (257us inferred) was single-buffered: 2 full-drain barriers per 128-row chunk,
// staging latency exposed. v3: chunks of 64 rows; next chunk prefetched into 4 named
// f32x4 regs BEFORE accumulating current chunk from LDS (issue-early/write-late).
// The diag block IS chunk b of the same slab -> separate Gd staging deleted.
// Accumulate sequence (row 4k+m -> u_m, ascending k, u's live across chunks) is
// bit-identical to R11/R12. All 4 waves execute identical barrier counts.
__global__ __launch_bounds__(256) void k_scan2(const float* __restrict__ W0,
        const float* __restrict__ B0, const float* __restrict__ G,
        const unsigned* __restrict__ postT, const float* __restrict__ popf,
        float* __restrict__ coef, float* __restrict__ alphaf) {
    __shared__ float Gs[64][68];     // 17.4 KB chunk buffer (pad 68: write<=4way, read free)
    __shared__ float ctab[4][1024];  // per-wave c history (16 KB)
    int tid = threadIdx.x;
    int wid = tid >> 6, lane = tid & 63;
    int r = blockIdx.x * 4 + wid;
    int crow = tid >> 2, ccol = (tid & 3) * 16;   // chunk loader: row 0..63, col 0..63
    #pragma unroll
    for (int kk = 0; kk < 16; ++kk) ctab[wid][kk * 64 + lane] = 0.f;
    const float* wr = W0 + (long)r * NN + lane * 32;
    f32x4 q0 = *(const f32x4*)(wr +  0), q1 = *(const f32x4*)(wr +  4);
    f32x4 q2 = *(const f32x4*)(wr +  8), q3 = *(const f32x4*)(wr + 12);
    f32x4 q4 = *(const f32x4*)(wr + 16), q5 = *(const f32x4*)(wr + 20);
    f32x4 q6 = *(const f32x4*)(wr + 24), q7 = *(const f32x4*)(wr + 28);
    f32x4 pp = q0*q0 + q1*q1 + q2*q2 + q3*q3 + q4*q4 + q5*q5 + q6*q6 + q7*q7;
    float nu = wave_sum64((pp.x + pp.y) + (pp.z + pp.w));
    float alpha = 1.f, inv_alpha = 1.f;
    { float t = fmaxf(nu, 1.f); alpha *= rsqrtf(t); inv_alpha *= sqrtf(t); nu = fminf(nu, 1.f); }
    float s0 = 1.f;

    f32x4 rg0, rg1, rg2, rg3;
    #define LOADCH(B, CH) { \
        const float* gsrc = G + (long)((CH) * 64 + crow) * SEQ + (B) * 64 + ccol; \
        rg0 = *(const f32x4*)(gsrc);      rg1 = *(const f32x4*)(gsrc + 4); \
        rg2 = *(const f32x4*)(gsrc + 8);  rg3 = *(const f32x4*)(gsrc + 12); }
    LOADCH(0, 0);

    for (int b = 0; b < 16; ++b) {
        float myB0  = B0[(long)r * SEQ + b * 64 + lane];
        float mypop = popf[b * 64 + lane];
        unsigned long long pm;
        {   unsigned lo = postT[r * 32 + 2 * b], hi = postT[r * 32 + 2 * b + 1];
            pm = ((unsigned long long)(unsigned)__builtin_amdgcn_readfirstlane((int)hi) << 32)
               |  (unsigned long long)(unsigned)__builtin_amdgcn_readfirstlane((int)lo);
        }
        float u0 = 0.f, u1 = 0.f, u2 = 0.f, u3 = 0.f;
        float cj = 0.f;
        for (int ch = 0; ch <= b; ++ch) {
            __syncthreads();                 // prior chunk's LDS reads complete
            *(f32x4*)&Gs[crow][ccol +  0] = rg0;
            *(f32x4*)&Gs[crow][ccol +  4] = rg1;
            *(f32x4*)&Gs[crow][ccol +  8] = rg2;
            *(f32x4*)&Gs[crow][ccol + 12] = rg3;
            __syncthreads();                 // chunk visible
            if (ch < b) {
                LOADCH(b, ch + 1);           // prefetch next chunk under accumulate
                int base = ch * 64;
                #pragma unroll 4
                for (int i = 0; i < 64; i += 4) {
                    f32x4 cq = *(const f32x4*)&ctab[wid][base + i];   // uniform bcast
                    u0 = fmaf(cq.x, Gs[i + 0][lane], u0);
                    u1 = fmaf(cq.y, Gs[i + 1][lane], u1);
                    u2 = fmaf(cq.z, Gs[i + 2][lane], u2);
                    u3 = fmaf(cq.w, Gs[i + 3][lane], u3);
                }
            } else {                         // ch == b: Gs holds the diag block
                if (b < 15) LOADCH(b + 1, 0);
                float acc = fmaf(s0, myB0, (u0 + u1) + (u2 + u3));
                #pragma unroll
                for (int j = 0; j < 64; ++j) {
                    if ((pm >> j) & 1ull) {  // wave-uniform branch
                        float dot = __int_as_float(__builtin_amdgcn_readlane(__float_as_int(acc), j));
                        float pj  = __int_as_float(__builtin_amdgcn_readlane(__float_as_int(mypop), j));
                        float c = LRC * inv_alpha;
                        nu = fmaf(2.f * LRC, alpha * dot, fmaf(LRC * LRC, pj, nu));
                        float t = fmaxf(nu, 1.f);
                        alpha *= rsqrtf(t); inv_alpha *= sqrtf(t); nu = fminf(nu, 1.f);
                        acc = fmaf(c, Gs[j][lane], acc);   // fold step j forward
                        cj = (lane == j) ? c : cj;
                    }
                }
            }
        }
        ctab[wid][b * 64 + lane] = cj;
        if (inv_alpha > 1e10f) {             // rescale event: fold alpha into V-space
            #pragma unroll 1
            for (int kk = 0; kk <= b; ++kk) ctab[wid][kk * 64 + lane] *= alpha;
            s0 *= alpha; alpha = 1.f; inv_alpha = 1.f;
        }
    }
    #undef LOADCH
    if (lane == 0) alphaf[r] = alpha * s0;
    #pragma unroll
    for (int kk = 0; kk < 16; ++kk)
        coef[(long)r * SEQ + kk * 64 + lane] = alpha * ctab[wid][kk * 64 + lane];
}

extern "C" void kernel_launch(void* const* d_in, const int* in_sizes, int n_in,
                              void* d_out, int out_size, void* d_ws, size_t ws_size,
                              hipStream_t stream) {
    const int*   tok     = (const int*)d_in[0];
    const float* sdr     = (const float*)d_in[1];
    const float* pos     = (const float*)d_in[2];
    const float* w_hippo = (const float*)d_in[3];
    const float* assoc   = (const float*)d_in[4];
    float* out = (float*)d_out;

    char* ws = (char*)d_ws;
    // Slot map (36.6 MB total, aliased by lifetime):
    unsigned short* Hh  = (unsigned short*)(ws);                 // 0-4 MB (dead after fixup)
    float*          G   = (float*)(ws);                          //   then G (gram, 4 MB)
    unsigned short* Wh  = (unsigned short*)(ws + (4l << 20));    // 4-12 MB (dead after dots)
    unsigned short* Sh  = Wh;                                    //   then assoc-bf16
    unsigned short* Ch  = Wh;                                    //   then coef-hi (4 MB)
    unsigned short* Cl  = (unsigned short*)(ws + (8l << 20));    //   coef-lo   (4 MB)
    unsigned short* Wl  = (unsigned short*)(ws + (12l << 20));   // 12-20 MB (dead after dots)
    float*          coef= (float*)(ws + (12l << 20));            //   then coef fp32 (8 MB)
    float*          dots= (float*)(ws + (20l << 20));            // 20-28 MB (dead after pack)
    float*          B0f = dots;                                  //   then B0 (8 MB)
    unsigned short* Xb  = (unsigned short*)(ws + (28l << 20));   // 28-32 MB
    unsigned short* XbT = (unsigned short*)(ws + (32l << 20));   // 32-36 MB
    unsigned* preT   = (unsigned*)(ws + (36l << 20));            // 256 KB
    unsigned* postT  = (unsigned*)(ws + (36l << 20) + 262144);   // 256 KB
    float*    popf   = (float*)(ws + (36l << 20) + 524288);      // 4 KB
    float*    alphaf = (float*)(ws + (36l << 20) + 532480);      // 8 KB

    k_hippo            <<<dim3(SEQ, 2),   256, 0, stream>>>(tok, sdr, pos, Hh);
    k_split            <<<2048,           256, 0, stream>>>(w_hippo, Wh, Wl);
    k_mgemm<SPLIT_B>   <<<dim3(16, 8),    256, 0, stream>>>(Hh, nullptr, Wh, Wl, dots,
                                                            1024, 2048, 2048, nullptr, nullptr);
    k_fixup            <<<8192,           256, 0, stream>>>(Hh, w_hippo, dots);
    k_pack             <<<SEQ,             64, 0, stream>>>(dots, preT, popf, Xb);
    k_packpost         <<<128,            256, 0, stream>>>(dots, postT);
    k_transpose        <<<dim3(16, 32),   256, 0, stream>>>(Xb, XbT);
    k_gram             <<<SEQ,            256, 0, stream>>>(preT, G);
    k_split            <<<2048,           256, 0, stream>>>(assoc, Sh, nullptr);
    k_mgemm<SPLIT_NONE><<<dim3(8, 16),    256, 0, stream>>>(Sh, nullptr, Xb, nullptr, B0f,
                                                            2048, 1024, 2048, nullptr, nullptr);
    k_scan2            <<<512,            256, 0, stream>>>(assoc, B0f, G, postT, popf, coef, alphaf);
    k_split            <<<1024,           256, 0, stream>>>(coef, Ch, Cl);
    k_mgemm<SPLIT_A>   <<<dim3(16, 16),   256, 0, stream>>>(Ch, Cl, XbT, nullptr, out,
                                                            2048, 2048, 1024, assoc, alphaf);
}

// Round 14
// 503.273 us; speedup vs baseline: 3.4139x; 1.3603x over previous
//
#include <hip/hip_runtime.h>
#include <hip/hip_bf16.h>

#define NT    10
#define NN    2048   // n_neurons
#define CA3C  2048
#define SEQ   1024
#define SPARS 0.05f
#define LRC   0.01f

typedef float          f32x4  __attribute__((ext_vector_type(4)));
typedef short          bf16x8 __attribute__((ext_vector_type(8)));
typedef unsigned short u16x4  __attribute__((ext_vector_type(4)));
typedef unsigned short u16x8  __attribute__((ext_vector_type(8)));

__device__ __forceinline__ unsigned short f2bf(float f) {   // RNE float->bf16 bits
    unsigned u = __float_as_uint(f);
    u += 0x7FFFu + ((u >> 16) & 1u);
    return (unsigned short)(u >> 16);
}
__device__ __forceinline__ float bf2f(unsigned short h) {
    return __uint_as_float(((unsigned)h) << 16);
}

// ---------------- Phase A: hippo_input (exact in bf16: values k*0.5, k<=30) --------
__global__ __launch_bounds__(256) void k_hippo(const int* __restrict__ tok,
        const float* __restrict__ sdr, const float* __restrict__ pos,
        unsigned short* __restrict__ Hh) {
    int s = blockIdx.x;
    int n = (blockIdx.y * 256 + threadIdx.x) * 4;
    const float* sp = sdr + (long)tok[s] * (NT * NN) + n;
    const float* pp = pos + (long)s * (NT * NN) + n;
    float a0 = 0.f, a1 = 0.f, a2 = 0.f, a3 = 0.f;
    #pragma unroll
    for (int t = 0; t < NT; ++t) {
        float4 sv = *(const float4*)(sp + t * NN);
        float4 pv = *(const float4*)(pp + t * NN);
        if (sv.x < SPARS) a0 += (pv.x < SPARS) ? 1.5f : 1.0f;
        if (sv.y < SPARS) a1 += (pv.y < SPARS) ? 1.5f : 1.0f;
        if (sv.z < SPARS) a2 += (pv.z < SPARS) ? 1.5f : 1.0f;
        if (sv.w < SPARS) a3 += (pv.w < SPARS) ? 1.5f : 1.0f;
    }
    u16x4 o = { f2bf(a0), f2bf(a1), f2bf(a2), f2bf(a3) };
    *(u16x4*)(Hh + (long)s * NN + n) = o;
}

// ---------------- split fp32 -> bf16 hi (+ optional lo residual) -------------------
__global__ __launch_bounds__(256) void k_split(const float* __restrict__ src,
        unsigned short* __restrict__ hi, unsigned short* __restrict__ lo) {
    long i = ((long)blockIdx.x * 256 + threadIdx.x) * 8;
    f32x4 x0 = *(const f32x4*)(src + i);
    f32x4 x1 = *(const f32x4*)(src + i + 4);
    float xs[8] = {x0.x, x0.y, x0.z, x0.w, x1.x, x1.y, x1.z, x1.w};
    u16x8 h, l;
    #pragma unroll
    for (int j = 0; j < 8; ++j) {
        unsigned short hb = f2bf(xs[j]);
        h[j] = hb;
        l[j] = f2bf(xs[j] - bf2f(hb));
    }
    *(u16x8*)(hi + i) = h;
    if (lo) *(u16x8*)(lo + i) = l;
}

// ---------------- MFMA GEMM v2 (unchanged from R12/R13): C = A @ B^T ---------------
#define SPLIT_NONE 0
#define SPLIT_A    1
#define SPLIT_B    2

template<int MODE>
__global__ __launch_bounds__(256, 1) void k_mgemm(
        const unsigned short* __restrict__ A0, const unsigned short* __restrict__ A1,
        const unsigned short* __restrict__ Bh, const unsigned short* __restrict__ B1,
        float* __restrict__ C, int M, int N, int K,
        const float* __restrict__ Wadd, const float* __restrict__ af) {
    __shared__ unsigned short LA[128 * 70], LB[128 * 70], LX[128 * 70];   // 17.9 KB each
    int tid = threadIdx.x, wid = tid >> 6, l = tid & 63;
    int m0 = blockIdx.y * 128, n0 = blockIdx.x * 128;
    int wr = wid >> 1, wc = wid & 1;
    int fr = l & 15, fk = l >> 4;
    f32x4 acc[4][4] = {};
    int srow = wid * 8 + (l >> 3);          // + i*32 -> rows 0..127
    int scol = (l & 7) * 8;                 // 16B chunk within 64-short row segment
    bf16x8 ra[4], rb[4], rx[4];
    #pragma unroll
    for (int i = 0; i < 4; ++i) {           // prefetch k-tile 0
        int row = i * 32 + srow;
        ra[i] = *(const bf16x8*)(A0 + (long)(m0 + row) * K + scol);
        rb[i] = *(const bf16x8*)(Bh + (long)(n0 + row) * K + scol);
        if (MODE == SPLIT_A) rx[i] = *(const bf16x8*)(A1 + (long)(m0 + row) * K + scol);
        if (MODE == SPLIT_B) rx[i] = *(const bf16x8*)(B1 + (long)(n0 + row) * K + scol);
    }
    for (int k0 = 0; k0 < K; k0 += 64) {
        __syncthreads();                    // prior tile's LDS reads done
        #pragma unroll
        for (int i = 0; i < 4; ++i) {
            int row = i * 32 + srow;
            *(bf16x8*)&LA[row * 70 + scol] = ra[i];
            *(bf16x8*)&LB[row * 70 + scol] = rb[i];
            if (MODE != SPLIT_NONE) *(bf16x8*)&LX[row * 70 + scol] = rx[i];
        }
        __syncthreads();                    // tile visible
        if (k0 + 64 < K) {                  // issue next tile's loads (hide under MFMA)
            #pragma unroll
            for (int i = 0; i < 4; ++i) {
                int row = i * 32 + srow;
                ra[i] = *(const bf16x8*)(A0 + (long)(m0 + row) * K + k0 + 64 + scol);
                rb[i] = *(const bf16x8*)(Bh + (long)(n0 + row) * K + k0 + 64 + scol);
                if (MODE == SPLIT_A) rx[i] = *(const bf16x8*)(A1 + (long)(m0 + row) * K + k0 + 64 + scol);
                if (MODE == SPLIT_B) rx[i] = *(const bf16x8*)(B1 + (long)(n0 + row) * K + k0 + 64 + scol);
            }
        }
        #pragma unroll
        for (int ks = 0; ks < 2; ++ks) {
            bf16x8 av[4], bv[4], xv[4];
            #pragma unroll
            for (int t = 0; t < 4; ++t) {
                av[t] = *(const bf16x8*)&LA[(wr * 64 + t * 16 + fr) * 70 + ks * 32 + fk * 8];
                bv[t] = *(const bf16x8*)&LB[(wc * 64 + t * 16 + fr) * 70 + ks * 32 + fk * 8];
                if (MODE == SPLIT_A) xv[t] = *(const bf16x8*)&LX[(wr * 64 + t * 16 + fr) * 70 + ks * 32 + fk * 8];
                if (MODE == SPLIT_B) xv[t] = *(const bf16x8*)&LX[(wc * 64 + t * 16 + fr) * 70 + ks * 32 + fk * 8];
            }
            #pragma unroll
            for (int mt = 0; mt < 4; ++mt)
                #pragma unroll
                for (int nt = 0; nt < 4; ++nt) {
                    acc[mt][nt] = __builtin_amdgcn_mfma_f32_16x16x32_bf16(av[mt], bv[nt], acc[mt][nt], 0, 0, 0);
                    if (MODE == SPLIT_A)
                        acc[mt][nt] = __builtin_amdgcn_mfma_f32_16x16x32_bf16(xv[mt], bv[nt], acc[mt][nt], 0, 0, 0);
                    if (MODE == SPLIT_B)
                        acc[mt][nt] = __builtin_amdgcn_mfma_f32_16x16x32_bf16(av[mt], xv[nt], acc[mt][nt], 0, 0, 0);
                }
        }
    }
    int drb = (l >> 4) * 4;
    #pragma unroll
    for (int mt = 0; mt < 4; ++mt)
        #pragma unroll
        for (int nt = 0; nt < 4; ++nt)
            #pragma unroll
            for (int e = 0; e < 4; ++e) {
                int row = m0 + wr * 64 + mt * 16 + drb + e;
                int cc  = n0 + wc * 64 + nt * 16 + (l & 15);
                float v = acc[mt][nt][e];
                if (Wadd) v = fmaf(af[row], Wadd[(long)row * N + cc], v);
                C[(long)row * N + cc] = v;
            }
}

// ---------------- fixup v2: flag+compact, then wave-parallel fp64 ------------------
// R13 form: ~6% of waves had >=1 flagged lane -> each paid the 2048-iter fp64 loop
// serially (~40us). v2: phase 1 ballot-compacts flagged indices (atomic append,
// order-independent final state); phase 2 runs ONE WAVE per flagged dot, 64-lane
// parallel fp64 dot + shfl reduce.
__global__ void k_zero(unsigned* cnt) { if (threadIdx.x == 0) *cnt = 0; }

__global__ __launch_bounds__(256) void k_fixflag(const float* __restrict__ dots,
        unsigned* __restrict__ list, unsigned* __restrict__ cnt) {
    int i = blockIdx.x * 256 + threadIdx.x;
    int lane = threadIdx.x & 63;
    bool f = fabsf(dots[i]) < 1e-3f;
    unsigned long long m = __ballot(f);
    if (m == 0) return;
    unsigned b0 = 0;
    if (lane == 0) b0 = atomicAdd(cnt, (unsigned)__popcll(m));
    b0 = __shfl(b0, 0, 64);
    if (f) {
        unsigned rank = (unsigned)__popcll(m & ((1ull << lane) - 1ull));
        list[b0 + rank] = (unsigned)i;
    }
}

__global__ __launch_bounds__(64) void k_fix64(const unsigned* __restrict__ list,
        const unsigned* __restrict__ cnt, const unsigned short* __restrict__ Hh,
        const float* __restrict__ w, float* __restrict__ dots) {
    int lane = threadIdx.x;
    unsigned n = *cnt;
    for (unsigned idx = blockIdx.x; idx < n; idx += gridDim.x) {
        unsigned i = list[idx];
        int s = (int)(i >> 11), c = (int)(i & 2047);
        const unsigned short* hr = Hh + (long)s * NN;
        const float* wr = w + (long)c * NN;
        double a = 0.0;
        #pragma unroll
        for (int j = 0; j < 8; ++j) {
            int k = j * 256 + lane * 4;
            f32x4 wv = *(const f32x4*)(wr + k);
            u16x4 hv = *(const u16x4*)(hr + k);
            a += (double)bf2f(hv.x) * (double)wv.x + (double)bf2f(hv.y) * (double)wv.y
               + (double)bf2f(hv.z) * (double)wv.z + (double)bf2f(hv.w) * (double)wv.w;
        }
        #pragma unroll
        for (int o = 1; o < 64; o <<= 1) a += __shfl_xor(a, o, 64);
        if (lane == 0) dots[i] = (a > 0.0) ? 1.0f : -1.0f;
    }
}

// ---------------- pack: preT[w][s] bits, popf[s], dense Xb bf16 (0/1 exact) --------
__global__ __launch_bounds__(64) void k_pack(const float* __restrict__ dots,
        unsigned* __restrict__ preT, float* __restrict__ popf,
        unsigned short* __restrict__ Xb) {
    int s = blockIdx.x;
    int w = threadIdx.x;
    const float* row = dots + (long)s * CA3C + w * 32;
    unsigned short* xrow = Xb + (long)s * CA3C + w * 32;
    unsigned m = 0;
    #pragma unroll
    for (int j4 = 0; j4 < 8; ++j4) {
        f32x4 v = *(const f32x4*)(row + j4 * 4);
        u16x4 xb;
        xb.x = v.x > 0.f ? 0x3F80 : 0; xb.y = v.y > 0.f ? 0x3F80 : 0;
        xb.z = v.z > 0.f ? 0x3F80 : 0; xb.w = v.w > 0.f ? 0x3F80 : 0;
        m |= (v.x > 0.f ? 1u : 0u) << (j4 * 4 + 0);
        m |= (v.y > 0.f ? 1u : 0u) << (j4 * 4 + 1);
        m |= (v.z > 0.f ? 1u : 0u) << (j4 * 4 + 2);
        m |= (v.w > 0.f ? 1u : 0u) << (j4 * 4 + 3);
        *(u16x4*)(xrow + j4 * 4) = xb;
    }
    preT[w * SEQ + s] = m;
    int pc = __popc(m);
    #pragma unroll
    for (int o = 1; o < 64; o <<= 1) pc += __shfl_xor(pc, o, 64);
    if (w == 0) popf[s] = (float)pc;
}

// ---------------- post bits: ballot-based 64x64 tile transpose (R13) ---------------
__global__ __launch_bounds__(256) void k_packpost(const float* __restrict__ dots,
        unsigned* __restrict__ postT) {
    __shared__ unsigned long long masks[4][64];
    int wid = threadIdx.x >> 6, lane = threadIdx.x & 63;
    int tile = blockIdx.x * 4 + wid;           // 0..511
    int rg = tile & 31, sg = tile >> 5;        // row-group 0..31, step-group 0..15
    int r0 = rg * 64;
    #pragma unroll 8
    for (int k = 0; k < 64; ++k) {
        int s = sg * 64 + k;                   // valid steps are 0..1022
        float d = (s < SEQ - 1) ? dots[(long)(s + 1) * CA3C + r0 + lane] : -1.f;
        unsigned long long m = __ballot(d > 0.f);
        if (lane == 0) masks[wid][k] = m;
    }
    unsigned w0 = 0, w1 = 0;
    #pragma unroll
    for (int k = 0; k < 32; ++k) {
        w0 |= (unsigned)((masks[wid][k]      >> lane) & 1ull) << k;
        w1 |= (unsigned)((masks[wid][k + 32] >> lane) & 1ull) << k;
    }
    postT[(r0 + lane) * 32 + sg * 2]     = w0;
    postT[(r0 + lane) * 32 + sg * 2 + 1] = w1;
}

// ---------------- transpose Xb[s][n] -> XbT[n][s] (bf16) ---------------------------
__global__ __launch_bounds__(256) void k_transpose(const unsigned short* __restrict__ Xb,
        unsigned short* __restrict__ XbT) {
    __shared__ unsigned short t[64][72];
    int s0 = blockIdx.x * 64, n0 = blockIdx.y * 64;
    int tx = threadIdx.x & 63, ty = threadIdx.x >> 6;
    #pragma unroll
    for (int ii = 0; ii < 16; ++ii) {
        int i = ty + ii * 4;
        t[i][tx] = Xb[(long)(s0 + i) * CA3C + n0 + tx];
    }
    __syncthreads();
    #pragma unroll
    for (int ii = 0; ii < 16; ++ii) {
        int i = ty + ii * 4;
        XbT[(long)(n0 + i) * SEQ + s0 + tx] = t[tx][i];
    }
}

// ---------------- Gram: G fp32 + EXACT bf16 hi/lo split (ints <=1024) --------------
__global__ __launch_bounds__(256) void k_gram(const unsigned* __restrict__ preT,
        float* __restrict__ G, unsigned short* __restrict__ Gbh,
        unsigned short* __restrict__ Gbl) {
    int i = blockIdx.x;
    int t = threadIdx.x;
    int a0 = 0, a1 = 0, a2 = 0, a3 = 0;
    #pragma unroll 8
    for (int w = 0; w < 64; ++w) {
        unsigned ri = preT[w * SEQ + i];       // uniform -> broadcast
        const unsigned* pr = preT + w * SEQ;
        a0 += __popc(ri & pr[t]);
        a1 += __popc(ri & pr[t + 256]);
        a2 += __popc(ri & pr[t + 512]);
        a3 += __popc(ri & pr[t + 768]);
    }
    long base = (long)i * SEQ;
    int vi[4] = {a0, a1, a2, a3};
    #pragma unroll
    for (int q = 0; q < 4; ++q) {
        long o = base + t + q * 256;
        float v = (float)vi[q];
        unsigned short h = f2bf(v);            // multiple-of-4 for v<1024: residual <=2
        G[o] = v;
        Gbh[o] = h;
        Gbl[o] = f2bf(v - bf2f(h));            // small int -> exact; split is EXACT
    }
}

// ---------------- DPP-based full-wave (64 lane) sum; broadcast via lane 63 ---------
__device__ __forceinline__ float wave_sum64(float x) {
    #define DPPADD(ctrl, rmask) \
        x += __int_as_float(__builtin_amdgcn_update_dpp(0, __float_as_int(x), ctrl, rmask, 0xF, true))
    DPPADD(0xB1, 0xF);
    DPPADD(0x4E, 0xF);
    DPPADD(0x141, 0xF);
    DPPADD(0x140, 0xF);
    DPPADD(0x142, 0xA);
    DPPADD(0x143, 0xC);
    #undef DPPADD
    return __int_as_float(__builtin_amdgcn_readlane(__float_as_int(x), 63));
}

// ---------------- Phase D v4: inter-block accumulation via MFMA --------------------
// R13's accumulate: 4 waves x 64 ds_read_b32 per 64-row chunk (identical data!) ->
// LDS-issue-bound (~2450 cyc/chunk/block). v4: u = c_hist . G_slab as MFMA:
// A = 8 rows (4 waves x c hi/lo, bf16 split, in LDS CHL), B = exact-bf16 G chunk
// (Gbh+Gbl, staged mgemm-style [kb][n][8]) -> 16 b128 frag reads + 16 MFMA per
// chunk per wave. Each wave computes the full 16x64 C (redundant, cheap) and
// extracts its own 2 rows (hi+lo c parts summed) via 4 ds_bpermute.
// Numerics: all bf16-split products exact; only the summation tree changes
// (~2^-16 relative on dots) -> no longer bit-identical, still << 1e-3 budget.
__global__ __launch_bounds__(256) void k_scan2(const float* __restrict__ W0,
        const float* __restrict__ B0, const float* __restrict__ G,
        const unsigned short* __restrict__ Gbh, const unsigned short* __restrict__ Gbl,
        const unsigned* __restrict__ postT, const float* __restrict__ popf,
        float* __restrict__ coef, float* __restrict__ alphaf) {
    __shared__ float Gd[64][68];               // diag fp32 (17.4 KB)
    __shared__ unsigned short BH[4096];        // B chunk hi [kb8][n64][8] (8 KB)
    __shared__ unsigned short BL[4096];        // B chunk lo (8 KB)
    __shared__ unsigned short CHL[8][1024];    // c rows 2w+p bf16 (16 KB)
    __shared__ float ctab[4][1024];            // c fp32 (16 KB)   total ~65.4 KB
    int tid = threadIdx.x, wid = tid >> 6, lane = tid & 63;
    int r = blockIdx.x * 4 + wid;
    int fr = lane & 15, fk = lane >> 4;
    int nl = tid >> 2, seg = tid & 3;          // stage loader indices
    #pragma unroll
    for (int kk = 0; kk < 16; ++kk) ctab[wid][kk * 64 + lane] = 0.f;
    const float* wr = W0 + (long)r * NN + lane * 32;
    f32x4 q0 = *(const f32x4*)(wr +  0), q1 = *(const f32x4*)(wr +  4);
    f32x4 q2 = *(const f32x4*)(wr +  8), q3 = *(const f32x4*)(wr + 12);
    f32x4 q4 = *(const f32x4*)(wr + 16), q5 = *(const f32x4*)(wr + 20);
    f32x4 q6 = *(const f32x4*)(wr + 24), q7 = *(const f32x4*)(wr + 28);
    f32x4 pp = q0*q0 + q1*q1 + q2*q2 + q3*q3 + q4*q4 + q5*q5 + q6*q6 + q7*q7;
    float nu = wave_sum64((pp.x + pp.y) + (pp.z + pp.w));
    float alpha = 1.f, inv_alpha = 1.f;
    { float t = fmaxf(nu, 1.f); alpha *= rsqrtf(t); inv_alpha *= sqrtf(t); nu = fminf(nu, 1.f); }
    float s0 = 1.f;

    bf16x8 ph0, ph1, pl0, pl1;
    for (int b = 0; b < 16; ++b) {
        __syncthreads();                       // prior b's LDS reads done; CHL visible
        {   // stage diag fp32 block
            const float* gs = G + (long)(b * 64 + nl) * SEQ + b * 64 + seg * 16;
            *(f32x4*)&Gd[nl][seg * 16 +  0] = *(const f32x4*)(gs +  0);
            *(f32x4*)&Gd[nl][seg * 16 +  4] = *(const f32x4*)(gs +  4);
            *(f32x4*)&Gd[nl][seg * 16 +  8] = *(const f32x4*)(gs +  8);
            *(f32x4*)&Gd[nl][seg * 16 + 12] = *(const f32x4*)(gs + 12);
        }
        f32x4 acc0 = {}, acc1 = {}, acc2 = {}, acc3 = {};
        if (b > 0) {                           // prefetch chunk 0
            const unsigned short* gh = Gbh + (long)(b * 64 + nl) * SEQ + seg * 16;
            const unsigned short* gl = Gbl + (long)(b * 64 + nl) * SEQ + seg * 16;
            ph0 = *(const bf16x8*)(gh); ph1 = *(const bf16x8*)(gh + 8);
            pl0 = *(const bf16x8*)(gl); pl1 = *(const bf16x8*)(gl + 8);
        }
        for (int ch = 0; ch < b; ++ch) {
            __syncthreads();                   // prior chunk frag reads done
            *(bf16x8*)&BH[((seg * 2 + 0) * 64 + nl) * 8] = ph0;
            *(bf16x8*)&BH[((seg * 2 + 1) * 64 + nl) * 8] = ph1;
            *(bf16x8*)&BL[((seg * 2 + 0) * 64 + nl) * 8] = pl0;
            *(bf16x8*)&BL[((seg * 2 + 1) * 64 + nl) * 8] = pl1;
            __syncthreads();                   // chunk visible
            if (ch + 1 < b) {                  // prefetch next under MFMA
                const unsigned short* gh = Gbh + (long)(b * 64 + nl) * SEQ + (ch + 1) * 64 + seg * 16;
                const unsigned short* gl = Gbl + (long)(b * 64 + nl) * SEQ + (ch + 1) * 64 + seg * 16;
                ph0 = *(const bf16x8*)(gh); ph1 = *(const bf16x8*)(gh + 8);
                pl0 = *(const bf16x8*)(gl); pl1 = *(const bf16x8*)(gl + 8);
            }
            #pragma unroll
            for (int kt = 0; kt < 2; ++kt) {
                bf16x8 af = *(const bf16x8*)&CHL[fr & 7][ch * 64 + kt * 32 + fk * 8];
                #define MTILE(T, ACC) { \
                    bf16x8 bh = *(const bf16x8*)&BH[((kt * 4 + fk) * 64 + T * 16 + fr) * 8]; \
                    bf16x8 bl = *(const bf16x8*)&BL[((kt * 4 + fk) * 64 + T * 16 + fr) * 8]; \
                    ACC = __builtin_amdgcn_mfma_f32_16x16x32_bf16(af, bh, ACC, 0, 0, 0); \
                    ACC = __builtin_amdgcn_mfma_f32_16x16x32_bf16(af, bl, ACC, 0, 0, 0); }
                MTILE(0, acc0) MTILE(1, acc1) MTILE(2, acc2) MTILE(3, acc3)
                #undef MTILE
            }
        }
        __syncthreads();                       // Gd staged; chunk reads done
        // extract u: wave w's rows 2w (c-hi) + 2w+1 (c-lo), col = lane
        float t0 = (wid & 1) ? (acc0.z + acc0.w) : (acc0.x + acc0.y);
        float t1 = (wid & 1) ? (acc1.z + acc1.w) : (acc1.x + acc1.y);
        float t2 = (wid & 1) ? (acc2.z + acc2.w) : (acc2.x + acc2.y);
        float t3 = (wid & 1) ? (acc3.z + acc3.w) : (acc3.x + acc3.y);
        int sa = (((wid >> 1) * 16) + fr) * 4;
        float p0 = __int_as_float(__builtin_amdgcn_ds_bpermute(sa, __float_as_int(t0)));
        float p1 = __int_as_float(__builtin_amdgcn_ds_bpermute(sa, __float_as_int(t1)));
        float p2 = __int_as_float(__builtin_amdgcn_ds_bpermute(sa, __float_as_int(t2)));
        float p3 = __int_as_float(__builtin_amdgcn_ds_bpermute(sa, __float_as_int(t3)));
        float u = (fk == 0) ? p0 : (fk == 1) ? p1 : (fk == 2) ? p2 : p3;

        float myB0  = B0[(long)r * SEQ + b * 64 + lane];
        float mypop = popf[b * 64 + lane];
        unsigned long long pm;
        {   unsigned lo = postT[r * 32 + 2 * b], hi = postT[r * 32 + 2 * b + 1];
            pm = ((unsigned long long)(unsigned)__builtin_amdgcn_readfirstlane((int)hi) << 32)
               |  (unsigned long long)(unsigned)__builtin_amdgcn_readfirstlane((int)lo);
        }
        float dacc = fmaf(s0, myB0, u);
        float cj = 0.f;
        #pragma unroll
        for (int j = 0; j < 64; ++j) {
            if ((pm >> j) & 1ull) {            // wave-uniform branch
                float dot = __int_as_float(__builtin_amdgcn_readlane(__float_as_int(dacc), j));
                float pj  = __int_as_float(__builtin_amdgcn_readlane(__float_as_int(mypop), j));
                float c = LRC * inv_alpha;
                nu = fmaf(2.f * LRC, alpha * dot, fmaf(LRC * LRC, pj, nu));
                float t = fmaxf(nu, 1.f);
                alpha *= rsqrtf(t); inv_alpha *= sqrtf(t); nu = fminf(nu, 1.f);
                dacc = fmaf(c, Gd[j][lane], dacc);   // fold step j forward
                cj = (lane == j) ? c : cj;
            }
        }
        ctab[wid][b * 64 + lane] = cj;
        {   unsigned short hh = f2bf(cj);
            CHL[wid * 2 + 0][b * 64 + lane] = hh;
            CHL[wid * 2 + 1][b * 64 + lane] = f2bf(cj - bf2f(hh));
        }
        if (inv_alpha > 1e10f) {               // rescale: fold alpha + re-split c's
            #pragma unroll 1
            for (int kk = 0; kk <= b; ++kk) {
                float v = ctab[wid][kk * 64 + lane] * alpha;
                ctab[wid][kk * 64 + lane] = v;
                unsigned short hh = f2bf(v);
                CHL[wid * 2 + 0][kk * 64 + lane] = hh;
                CHL[wid * 2 + 1][kk * 64 + lane] = f2bf(v - bf2f(hh));
            }
            s0 *= alpha; alpha = 1.f; inv_alpha = 1.f;
        }
    }
    if (lane == 0) alphaf[r] = alpha * s0;
    #pragma unroll
    for (int kk = 0; kk < 16; ++kk)
        coef[(long)r * SEQ + kk * 64 + lane] = alpha * ctab[wid][kk * 64 + lane];
}

extern "C" void kernel_launch(void* const* d_in, const int* in_sizes, int n_in,
                              void* d_out, int out_size, void* d_ws, size_t ws_size,
                              hipStream_t stream) {
    const int*   tok     = (const int*)d_in[0];
    const float* sdr     = (const float*)d_in[1];
    const float* pos     = (const float*)d_in[2];
    const float* w_hippo = (const float*)d_in[3];
    const float* assoc   = (const float*)d_in[4];
    float* out = (float*)d_out;

    char* ws = (char*)d_ws;
    // Slot map (38.1 MB, aliased by lifetime):
    unsigned short* Hh  = (unsigned short*)(ws);                 // 0-4 MB (dead after fix64)
    float*          G   = (float*)(ws);                          //   then G fp32 (4 MB)
    unsigned short* Wh  = (unsigned short*)(ws + (4l << 20));    // 4-12 (dead after dots)
    unsigned short* Sh  = Wh;                                    //   then assoc-bf16 (8 MB)
    unsigned short* Ch  = Wh;                                    //   then coef-hi (4 MB)
    unsigned short* Cl  = (unsigned short*)(ws + (8l << 20));    //   coef-lo (4 MB)
    unsigned short* Wl  = (unsigned short*)(ws + (12l << 20));   // 12-20 (dead after dots)
    float*          coef= (float*)(ws + (12l << 20));            //   then coef fp32 (8 MB)
    float*          dots= (float*)(ws + (20l << 20));            // 20-28 (dead after pack)
    float*          B0f = dots;                                  //   then B0 (8 MB)
    unsigned short* Xb  = (unsigned short*)(ws + (28l << 20));   // 28-32 (dead after B0 gemm)
    unsigned short* Gbh = Xb;                                    //   then G-bf16 hi (2 MB)
    unsigned short* Gbl = (unsigned short*)(ws + (30l << 20));   //   G-bf16 lo (2 MB)
    unsigned short* XbT = (unsigned short*)(ws + (32l << 20));   // 32-36 MB
    unsigned* preT   = (unsigned*)(ws + (36l << 20));            // 256 KB
    unsigned* postT  = (unsigned*)(ws + (36l << 20) + 262144);   // 256 KB
    float*    popf   = (float*)(ws + (36l << 20) + 524288);      // 4 KB
    float*    alphaf = (float*)(ws + (36l << 20) + 532480);      // 8 KB
    unsigned* cnt    = (unsigned*)(ws + (37l << 20));            // 4 B
    unsigned* list   = (unsigned*)(ws + (37l << 20) + 4096);     // 1 MB

    k_hippo            <<<dim3(SEQ, 2),   256, 0, stream>>>(tok, sdr, pos, Hh);
    k_split            <<<2048,           256, 0, stream>>>(w_hippo, Wh, Wl);
    k_mgemm<SPLIT_B>   <<<dim3(16, 8),    256, 0, stream>>>(Hh, nullptr, Wh, Wl, dots,
                                                            1024, 2048, 2048, nullptr, nullptr);
    k_zero             <<<1,               64, 0, stream>>>(cnt);
    k_fixflag          <<<8192,           256, 0, stream>>>(dots, list, cnt);
    k_fix64            <<<2048,            64, 0, stream>>>(list, cnt, Hh, w_hippo, dots);
    k_pack             <<<SEQ,             64, 0, stream>>>(dots, preT, popf, Xb);
    k_packpost         <<<128,            256, 0, stream>>>(dots, postT);
    k_transpose        <<<dim3(16, 32),   256, 0, stream>>>(Xb, XbT);
    k_split            <<<2048,           256, 0, stream>>>(assoc, Sh, nullptr);
    k_mgemm<SPLIT_NONE><<<dim3(8, 16),    256, 0, stream>>>(Sh, nullptr, Xb, nullptr, B0f,
                                                            2048, 1024, 2048, nullptr, nullptr);
    k_gram             <<<SEQ,            256, 0, stream>>>(preT, G, Gbh, Gbl);  // after B0: Gb* over dead Xb
    k_scan2            <<<512,            256, 0, stream>>>(assoc, B0f, G, Gbh, Gbl,
                                                            postT, popf, coef, alphaf);
    k_split            <<<1024,           256, 0, stream>>>(coef, Ch, Cl);
    k_mgemm<SPLIT_A>   <<<dim3(16, 16),   256, 0, stream>>>(Ch, Cl, XbT, nullptr, out,
                                                            2048, 2048, 1024, assoc, alphaf);
}

// Round 15
// 464.856 us; speedup vs baseline: 3.6960x; 1.0826x over previous
//
#include <hip/hip_runtime.h>
#include <hip/hip_bf16.h>

#define NT    10
#define NN    2048   // n_neurons
#define CA3C  2048
#define SEQ   1024
#define SPARS 0.05f
#define LRC   0.01f

typedef float          f32x4  __attribute__((ext_vector_type(4)));
typedef short          bf16x8 __attribute__((ext_vector_type(8)));
typedef unsigned short u16x4  __attribute__((ext_vector_type(4)));
typedef unsigned short u16x8  __attribute__((ext_vector_type(8)));

__device__ __forceinline__ unsigned short f2bf(float f) {   // RNE float->bf16 bits
    unsigned u = __float_as_uint(f);
    u += 0x7FFFu + ((u >> 16) & 1u);
    return (unsigned short)(u >> 16);
}
__device__ __forceinline__ float bf2f(unsigned short h) {
    return __uint_as_float(((unsigned)h) << 16);
}

// ---------------- Phase A: hippo_input (exact in bf16); also zeroes fixup cnt ------
__global__ __launch_bounds__(256) void k_hippo(const int* __restrict__ tok,
        const float* __restrict__ sdr, const float* __restrict__ pos,
        unsigned short* __restrict__ Hh, unsigned* __restrict__ cnt) {
    if (blockIdx.x == 0 && blockIdx.y == 0 && threadIdx.x == 0) *cnt = 0;
    int s = blockIdx.x;
    int n = (blockIdx.y * 256 + threadIdx.x) * 4;
    const float* sp = sdr + (long)tok[s] * (NT * NN) + n;
    const float* pp = pos + (long)s * (NT * NN) + n;
    float a0 = 0.f, a1 = 0.f, a2 = 0.f, a3 = 0.f;
    #pragma unroll
    for (int t = 0; t < NT; ++t) {
        float4 sv = *(const float4*)(sp + t * NN);
        float4 pv = *(const float4*)(pp + t * NN);
        if (sv.x < SPARS) a0 += (pv.x < SPARS) ? 1.5f : 1.0f;
        if (sv.y < SPARS) a1 += (pv.y < SPARS) ? 1.5f : 1.0f;
        if (sv.z < SPARS) a2 += (pv.z < SPARS) ? 1.5f : 1.0f;
        if (sv.w < SPARS) a3 += (pv.w < SPARS) ? 1.5f : 1.0f;
    }
    u16x4 o = { f2bf(a0), f2bf(a1), f2bf(a2), f2bf(a3) };
    *(u16x4*)(Hh + (long)s * NN + n) = o;
}

// ---------------- fused splits: w_hippo -> Wh+Wl ; assoc -> Sh ---------------------
__device__ __forceinline__ void split8(const float* __restrict__ src,
        unsigned short* __restrict__ hi, unsigned short* __restrict__ lo, long blk) {
    long i = (blk * 256 + threadIdx.x) * 8;
    f32x4 x0 = *(const f32x4*)(src + i);
    f32x4 x1 = *(const f32x4*)(src + i + 4);
    float xs[8] = {x0.x, x0.y, x0.z, x0.w, x1.x, x1.y, x1.z, x1.w};
    u16x8 h, l;
    #pragma unroll
    for (int j = 0; j < 8; ++j) {
        unsigned short hb = f2bf(xs[j]);
        h[j] = hb;
        l[j] = f2bf(xs[j] - bf2f(hb));
    }
    *(u16x8*)(hi + i) = h;
    if (lo) *(u16x8*)(lo + i) = l;
}

__global__ __launch_bounds__(256) void k_splits(const float* __restrict__ w_hippo,
        unsigned short* __restrict__ Wh, unsigned short* __restrict__ Wl,
        const float* __restrict__ assoc, unsigned short* __restrict__ Sh) {
    long b = blockIdx.x;
    if (b < 2048) split8(w_hippo, Wh, Wl, b);
    else         split8(assoc, Sh, nullptr, b - 2048);
}

// ---------------- MFMA GEMM v3: C = A @ B^T, templated N-tile ----------------------
// BN=128: 4 waves x 64x64 (as R12-R14). BN=64: 4 waves x 64x32 -> 2x blocks, fills
// the machine for M=1024/N=1024 shapes (R14 ran dots/B0 at 128 blocks = half idle).
#define SPLIT_NONE 0
#define SPLIT_A    1
#define SPLIT_B    2

template<int MODE, int BN>
__global__ __launch_bounds__(256, 1) void k_mgemm(
        const unsigned short* __restrict__ A0, const unsigned short* __restrict__ A1,
        const unsigned short* __restrict__ Bh, const unsigned short* __restrict__ B1,
        float* __restrict__ C, int M, int N, int K,
        const float* __restrict__ Wadd, const float* __restrict__ af) {
    constexpr int NTW = BN / 32;            // N-tiles per wave (16-wide each)
    constexpr int XR  = (MODE == SPLIT_A) ? 128 : BN;   // LX rows
    __shared__ unsigned short LA[128 * 70];
    __shared__ unsigned short LB[BN * 70];
    __shared__ unsigned short LX[(MODE == SPLIT_NONE) ? 70 : XR * 70];
    int tid = threadIdx.x, wid = tid >> 6, l = tid & 63;
    int m0 = blockIdx.y * 128, n0 = blockIdx.x * BN;
    int wr = wid >> 1, wc = wid & 1;
    int fr = l & 15, fk = l >> 4;
    f32x4 acc[4][NTW] = {};
    int srow = wid * 8 + (l >> 3);          // 0..31; +i*32 -> rows
    int scol = (l & 7) * 8;
    bf16x8 ra[4], rb[BN / 32], rx[XR / 32];
    #pragma unroll
    for (int i = 0; i < 4; ++i)
        ra[i] = *(const bf16x8*)(A0 + (long)(m0 + i * 32 + srow) * K + scol);
    #pragma unroll
    for (int i = 0; i < BN / 32; ++i)
        rb[i] = *(const bf16x8*)(Bh + (long)(n0 + i * 32 + srow) * K + scol);
    if (MODE == SPLIT_A)
        #pragma unroll
        for (int i = 0; i < XR / 32; ++i)
            rx[i] = *(const bf16x8*)(A1 + (long)(m0 + i * 32 + srow) * K + scol);
    if (MODE == SPLIT_B)
        #pragma unroll
        for (int i = 0; i < XR / 32; ++i)
            rx[i] = *(const bf16x8*)(B1 + (long)(n0 + i * 32 + srow) * K + scol);

    for (int k0 = 0; k0 < K; k0 += 64) {
        __syncthreads();
        #pragma unroll
        for (int i = 0; i < 4; ++i) *(bf16x8*)&LA[(i * 32 + srow) * 70 + scol] = ra[i];
        #pragma unroll
        for (int i = 0; i < BN / 32; ++i) *(bf16x8*)&LB[(i * 32 + srow) * 70 + scol] = rb[i];
        if (MODE != SPLIT_NONE)
            #pragma unroll
            for (int i = 0; i < XR / 32; ++i) *(bf16x8*)&LX[(i * 32 + srow) * 70 + scol] = rx[i];
        __syncthreads();
        if (k0 + 64 < K) {
            int kn = k0 + 64;
            #pragma unroll
            for (int i = 0; i < 4; ++i)
                ra[i] = *(const bf16x8*)(A0 + (long)(m0 + i * 32 + srow) * K + kn + scol);
            #pragma unroll
            for (int i = 0; i < BN / 32; ++i)
                rb[i] = *(const bf16x8*)(Bh + (long)(n0 + i * 32 + srow) * K + kn + scol);
            if (MODE == SPLIT_A)
                #pragma unroll
                for (int i = 0; i < XR / 32; ++i)
                    rx[i] = *(const bf16x8*)(A1 + (long)(m0 + i * 32 + srow) * K + kn + scol);
            if (MODE == SPLIT_B)
                #pragma unroll
                for (int i = 0; i < XR / 32; ++i)
                    rx[i] = *(const bf16x8*)(B1 + (long)(n0 + i * 32 + srow) * K + kn + scol);
        }
        #pragma unroll
        for (int ks = 0; ks < 2; ++ks) {
            bf16x8 av[4], bv[NTW], xv[4];
            #pragma unroll
            for (int t = 0; t < 4; ++t)
                av[t] = *(const bf16x8*)&LA[(wr * 64 + t * 16 + fr) * 70 + ks * 32 + fk * 8];
            #pragma unroll
            for (int t = 0; t < NTW; ++t)
                bv[t] = *(const bf16x8*)&LB[(wc * (BN / 2) + t * 16 + fr) * 70 + ks * 32 + fk * 8];
            if (MODE == SPLIT_A)
                #pragma unroll
                for (int t = 0; t < 4; ++t)
                    xv[t] = *(const bf16x8*)&LX[(wr * 64 + t * 16 + fr) * 70 + ks * 32 + fk * 8];
            if (MODE == SPLIT_B)
                #pragma unroll
                for (int t = 0; t < NTW; ++t)
                    xv[t] = *(const bf16x8*)&LX[(wc * (BN / 2) + t * 16 + fr) * 70 + ks * 32 + fk * 8];
            #pragma unroll
            for (int mt = 0; mt < 4; ++mt)
                #pragma unroll
                for (int nt = 0; nt < NTW; ++nt) {
                    acc[mt][nt] = __builtin_amdgcn_mfma_f32_16x16x32_bf16(av[mt], bv[nt], acc[mt][nt], 0, 0, 0);
                    if (MODE == SPLIT_A)
                        acc[mt][nt] = __builtin_amdgcn_mfma_f32_16x16x32_bf16(xv[mt], bv[nt], acc[mt][nt], 0, 0, 0);
                    if (MODE == SPLIT_B)
                        acc[mt][nt] = __builtin_amdgcn_mfma_f32_16x16x32_bf16(av[mt], xv[nt], acc[mt][nt], 0, 0, 0);
                }
        }
    }
    int drb = (l >> 4) * 4;
    #pragma unroll
    for (int mt = 0; mt < 4; ++mt)
        #pragma unroll
        for (int nt = 0; nt < NTW; ++nt)
            #pragma unroll
            for (int e = 0; e < 4; ++e) {
                int row = m0 + wr * 64 + mt * 16 + drb + e;
                int cc  = n0 + wc * (BN / 2) + nt * 16 + (l & 15);
                float v = acc[mt][nt][e];
                if (Wadd) v = fmaf(af[row], Wadd[(long)row * N + cc], v);
                C[(long)row * N + cc] = v;
            }
}

// ---------------- fixup: flag+compact, then wave-parallel fp64 ---------------------
__global__ __launch_bounds__(256) void k_fixflag(const float* __restrict__ dots,
        unsigned* __restrict__ list, unsigned* __restrict__ cnt) {
    int i = blockIdx.x * 256 + threadIdx.x;
    int lane = threadIdx.x & 63;
    bool f = fabsf(dots[i]) < 1e-3f;
    unsigned long long m = __ballot(f);
    if (m == 0) return;
    unsigned b0 = 0;
    if (lane == 0) b0 = atomicAdd(cnt, (unsigned)__popcll(m));
    b0 = __shfl(b0, 0, 64);
    if (f) {
        unsigned rank = (unsigned)__popcll(m & ((1ull << lane) - 1ull));
        list[b0 + rank] = (unsigned)i;
    }
}

__global__ __launch_bounds__(64) void k_fix64(const unsigned* __restrict__ list,
        const unsigned* __restrict__ cnt, const unsigned short* __restrict__ Hh,
        const float* __restrict__ w, float* __restrict__ dots) {
    int lane = threadIdx.x;
    unsigned n = *cnt;
    for (unsigned idx = blockIdx.x; idx < n; idx += gridDim.x) {
        unsigned i = list[idx];
        int s = (int)(i >> 11), c = (int)(i & 2047);
        const unsigned short* hr = Hh + (long)s * NN;
        const float* wr = w + (long)c * NN;
        double a = 0.0;
        #pragma unroll
        for (int j = 0; j < 8; ++j) {
            int k = j * 256 + lane * 4;
            f32x4 wv = *(const f32x4*)(wr + k);
            u16x4 hv = *(const u16x4*)(hr + k);
            a += (double)bf2f(hv.x) * (double)wv.x + (double)bf2f(hv.y) * (double)wv.y
               + (double)bf2f(hv.z) * (double)wv.z + (double)bf2f(hv.w) * (double)wv.w;
        }
        #pragma unroll
        for (int o = 1; o < 64; o <<= 1) a += __shfl_xor(a, o, 64);
        if (lane == 0) dots[i] = (a > 0.0) ? 1.0f : -1.0f;
    }
}

// ---------------- fused pack (blocks 0..255, 4 s each) + packpost (256..383) -------
__global__ __launch_bounds__(256) void k_packx(const float* __restrict__ dots,
        unsigned* __restrict__ preT, float* __restrict__ popf,
        unsigned short* __restrict__ Xb, unsigned* __restrict__ postT) {
    int wid = threadIdx.x >> 6, lane = threadIdx.x & 63;
    if (blockIdx.x < 256) {
        int s = blockIdx.x * 4 + wid;
        const float* row = dots + (long)s * CA3C + lane * 32;
        unsigned short* xrow = Xb + (long)s * CA3C + lane * 32;
        unsigned m = 0;
        #pragma unroll
        for (int j4 = 0; j4 < 8; ++j4) {
            f32x4 v = *(const f32x4*)(row + j4 * 4);
            u16x4 xb;
            xb.x = v.x > 0.f ? 0x3F80 : 0; xb.y = v.y > 0.f ? 0x3F80 : 0;
            xb.z = v.z > 0.f ? 0x3F80 : 0; xb.w = v.w > 0.f ? 0x3F80 : 0;
            m |= (v.x > 0.f ? 1u : 0u) << (j4 * 4 + 0);
            m |= (v.y > 0.f ? 1u : 0u) << (j4 * 4 + 1);
            m |= (v.z > 0.f ? 1u : 0u) << (j4 * 4 + 2);
            m |= (v.w > 0.f ? 1u : 0u) << (j4 * 4 + 3);
            *(u16x4*)(xrow + j4 * 4) = xb;
        }
        preT[lane * SEQ + s] = m;
        int pc = __popc(m);
        #pragma unroll
        for (int o = 1; o < 64; o <<= 1) pc += __shfl_xor(pc, o, 64);
        if (lane == 0) popf[s] = (float)pc;
    } else {
        __shared__ unsigned long long masks[4][64];
        int tile = (blockIdx.x - 256) * 4 + wid;   // 0..511
        int rg = tile & 31, sg = tile >> 5;
        int r0 = rg * 64;
        #pragma unroll 8
        for (int k = 0; k < 64; ++k) {
            int s = sg * 64 + k;
            float d = (s < SEQ - 1) ? dots[(long)(s + 1) * CA3C + r0 + lane] : -1.f;
            unsigned long long m = __ballot(d > 0.f);
            if (lane == 0) masks[wid][k] = m;
        }
        unsigned w0 = 0, w1 = 0;
        #pragma unroll
        for (int k = 0; k < 32; ++k) {
            w0 |= (unsigned)((masks[wid][k]      >> lane) & 1ull) << k;
            w1 |= (unsigned)((masks[wid][k + 32] >> lane) & 1ull) << k;
        }
        postT[(r0 + lane) * 32 + sg * 2]     = w0;
        postT[(r0 + lane) * 32 + sg * 2 + 1] = w1;
    }
}

// ---------------- transpose Xb[s][n] -> XbT[n][s] (bf16) ---------------------------
__global__ __launch_bounds__(256) void k_transpose(const unsigned short* __restrict__ Xb,
        unsigned short* __restrict__ XbT) {
    __shared__ unsigned short t[64][72];
    int s0 = blockIdx.x * 64, n0 = blockIdx.y * 64;
    int tx = threadIdx.x & 63, ty = threadIdx.x >> 6;
    #pragma unroll
    for (int ii = 0; ii < 16; ++ii) {
        int i = ty + ii * 4;
        t[i][tx] = Xb[(long)(s0 + i) * CA3C + n0 + tx];
    }
    __syncthreads();
    #pragma unroll
    for (int ii = 0; ii < 16; ++ii) {
        int i = ty + ii * 4;
        XbT[(long)(n0 + i) * SEQ + s0 + tx] = t[tx][i];
    }
}

// ---------------- Gram: G fp32 + EXACT bf16 hi/lo split ----------------------------
__global__ __launch_bounds__(256) void k_gram(const unsigned* __restrict__ preT,
        float* __restrict__ G, unsigned short* __restrict__ Gbh,
        unsigned short* __restrict__ Gbl) {
    int i = blockIdx.x;
    int t = threadIdx.x;
    int a0 = 0, a1 = 0, a2 = 0, a3 = 0;
    #pragma unroll 8
    for (int w = 0; w < 64; ++w) {
        unsigned ri = preT[w * SEQ + i];
        const unsigned* pr = preT + w * SEQ;
        a0 += __popc(ri & pr[t]);
        a1 += __popc(ri & pr[t + 256]);
        a2 += __popc(ri & pr[t + 512]);
        a3 += __popc(ri & pr[t + 768]);
    }
    long base = (long)i * SEQ;
    int vi[4] = {a0, a1, a2, a3};
    #pragma unroll
    for (int q = 0; q < 4; ++q) {
        long o = base + t + q * 256;
        float v = (float)vi[q];
        unsigned short h = f2bf(v);
        G[o] = v;
        Gbh[o] = h;
        Gbl[o] = f2bf(v - bf2f(h));
    }
}

// ---------------- DPP-based full-wave (64 lane) sum --------------------------------
__device__ __forceinline__ float wave_sum64(float x) {
    #define DPPADD(ctrl, rmask) \
        x += __int_as_float(__builtin_amdgcn_update_dpp(0, __float_as_int(x), ctrl, rmask, 0xF, true))
    DPPADD(0xB1, 0xF);
    DPPADD(0x4E, 0xF);
    DPPADD(0x141, 0xF);
    DPPADD(0x140, 0xF);
    DPPADD(0x142, 0xA);
    DPPADD(0x143, 0xC);
    #undef DPPADD
    return __int_as_float(__builtin_amdgcn_readlane(__float_as_int(x), 63));
}

// ---------------- Phase D v5: MFMA inter-block + BH/BL ping-pong -------------------
// vs v4: (1) double-buffered B chunks -> 1 barrier/chunk (152 total vs 270);
// (2) ctab deleted -- c lives only as bf16 hi/lo in CHL (reconstruction hi+lo
// captures all but ~2^-25 rel); (3) writes Ch/Cl (bf16 split of alpha*c) directly,
// so the separate coef-split kernel is gone.
__global__ __launch_bounds__(256) void k_scan2(const float* __restrict__ W0,
        const float* __restrict__ B0, const float* __restrict__ G,
        const unsigned short* __restrict__ Gbh, const unsigned short* __restrict__ Gbl,
        const unsigned* __restrict__ postT, const float* __restrict__ popf,
        unsigned short* __restrict__ Ch, unsigned short* __restrict__ Cl,
        float* __restrict__ alphaf) {
    __shared__ float Gd[64][68];               // 17.4 KB
    __shared__ unsigned short BH[2][4096];     // 16 KB (ping-pong)
    __shared__ unsigned short BL[2][4096];     // 16 KB
    __shared__ unsigned short CHL[8][1024];    // 16 KB   total 65.4 KB
    int tid = threadIdx.x, wid = tid >> 6, lane = tid & 63;
    int r = blockIdx.x * 4 + wid;
    int fr = lane & 15, fk = lane >> 4;
    int nl = tid >> 2, seg = tid & 3;
    const float* wr = W0 + (long)r * NN + lane * 32;
    f32x4 q0 = *(const f32x4*)(wr +  0), q1 = *(const f32x4*)(wr +  4);
    f32x4 q2 = *(const f32x4*)(wr +  8), q3 = *(const f32x4*)(wr + 12);
    f32x4 q4 = *(const f32x4*)(wr + 16), q5 = *(const f32x4*)(wr + 20);
    f32x4 q6 = *(const f32x4*)(wr + 24), q7 = *(const f32x4*)(wr + 28);
    f32x4 pp = q0*q0 + q1*q1 + q2*q2 + q3*q3 + q4*q4 + q5*q5 + q6*q6 + q7*q7;
    float nu = wave_sum64((pp.x + pp.y) + (pp.z + pp.w));
    float alpha = 1.f, inv_alpha = 1.f;
    { float t = fmaxf(nu, 1.f); alpha *= rsqrtf(t); inv_alpha *= sqrtf(t); nu = fminf(nu, 1.f); }
    float s0 = 1.f;

    bf16x8 ph0, ph1, pl0, pl1;
    for (int b = 0; b < 16; ++b) {
        __syncthreads();                       // prior b's Gd/CHL/BH reads done
        {   // stage diag fp32 block
            const float* gs = G + (long)(b * 64 + nl) * SEQ + b * 64 + seg * 16;
            *(f32x4*)&Gd[nl][seg * 16 +  0] = *(const f32x4*)(gs +  0);
            *(f32x4*)&Gd[nl][seg * 16 +  4] = *(const f32x4*)(gs +  4);
            *(f32x4*)&Gd[nl][seg * 16 +  8] = *(const f32x4*)(gs +  8);
            *(f32x4*)&Gd[nl][seg * 16 + 12] = *(const f32x4*)(gs + 12);
        }
        if (b > 0) {                           // load + write chunk 0 into buf 0
            const unsigned short* gh = Gbh + (long)(b * 64 + nl) * SEQ + seg * 16;
            const unsigned short* gl = Gbl + (long)(b * 64 + nl) * SEQ + seg * 16;
            ph0 = *(const bf16x8*)(gh); ph1 = *(const bf16x8*)(gh + 8);
            pl0 = *(const bf16x8*)(gl); pl1 = *(const bf16x8*)(gl + 8);
            *(bf16x8*)&BH[0][((seg * 2 + 0) * 64 + nl) * 8] = ph0;
            *(bf16x8*)&BH[0][((seg * 2 + 1) * 64 + nl) * 8] = ph1;
            *(bf16x8*)&BL[0][((seg * 2 + 0) * 64 + nl) * 8] = pl0;
            *(bf16x8*)&BL[0][((seg * 2 + 1) * 64 + nl) * 8] = pl1;
        }
        __syncthreads();                       // Gd + buf0 visible
        f32x4 acc0 = {}, acc1 = {}, acc2 = {}, acc3 = {};
        for (int ch = 0; ch < b; ++ch) {
            if (ch + 1 < b) {                  // prefetch next chunk into regs
                const unsigned short* gh = Gbh + (long)(b * 64 + nl) * SEQ + (ch + 1) * 64 + seg * 16;
                const unsigned short* gl = Gbl + (long)(b * 64 + nl) * SEQ + (ch + 1) * 64 + seg * 16;
                ph0 = *(const bf16x8*)(gh); ph1 = *(const bf16x8*)(gh + 8);
                pl0 = *(const bf16x8*)(gl); pl1 = *(const bf16x8*)(gl + 8);
            }
            const unsigned short* bh = BH[ch & 1];
            const unsigned short* bl = BL[ch & 1];
            #pragma unroll
            for (int kt = 0; kt < 2; ++kt) {
                bf16x8 af = *(const bf16x8*)&CHL[fr & 7][ch * 64 + kt * 32 + fk * 8];
                #define MTILE(T, ACC) { \
                    bf16x8 vh = *(const bf16x8*)&bh[((kt * 4 + fk) * 64 + T * 16 + fr) * 8]; \
                    bf16x8 vl = *(const bf16x8*)&bl[((kt * 4 + fk) * 64 + T * 16 + fr) * 8]; \
                    ACC = __builtin_amdgcn_mfma_f32_16x16x32_bf16(af, vh, ACC, 0, 0, 0); \
                    ACC = __builtin_amdgcn_mfma_f32_16x16x32_bf16(af, vl, ACC, 0, 0, 0); }
                MTILE(0, acc0) MTILE(1, acc1) MTILE(2, acc2) MTILE(3, acc3)
                #undef MTILE
            }
            if (ch + 1 < b) {                  // write next chunk into other buffer
                int nb = (ch + 1) & 1;
                *(bf16x8*)&BH[nb][((seg * 2 + 0) * 64 + nl) * 8] = ph0;
                *(bf16x8*)&BH[nb][((seg * 2 + 1) * 64 + nl) * 8] = ph1;
                *(bf16x8*)&BL[nb][((seg * 2 + 0) * 64 + nl) * 8] = pl0;
                *(bf16x8*)&BL[nb][((seg * 2 + 1) * 64 + nl) * 8] = pl1;
            }
            __syncthreads();                   // next buf visible / this buf free
        }
        // extract u: wave w's rows 2w (c-hi) + 2w+1 (c-lo), col = lane
        float t0 = (wid & 1) ? (acc0.z + acc0.w) : (acc0.x + acc0.y);
        float t1 = (wid & 1) ? (acc1.z + acc1.w) : (acc1.x + acc1.y);
        float t2 = (wid & 1) ? (acc2.z + acc2.w) : (acc2.x + acc2.y);
        float t3 = (wid & 1) ? (acc3.z + acc3.w) : (acc3.x + acc3.y);
        int sa = (((wid >> 1) * 16) + fr) * 4;
        float p0 = __int_as_float(__builtin_amdgcn_ds_bpermute(sa, __float_as_int(t0)));
        float p1 = __int_as_float(__builtin_amdgcn_ds_bpermute(sa, __float_as_int(t1)));
        float p2 = __int_as_float(__builtin_amdgcn_ds_bpermute(sa, __float_as_int(t2)));
        float p3 = __int_as_float(__builtin_amdgcn_ds_bpermute(sa, __float_as_int(t3)));
        float u = (fk == 0) ? p0 : (fk == 1) ? p1 : (fk == 2) ? p2 : p3;

        float myB0  = B0[(long)r * SEQ + b * 64 + lane];
        float mypop = popf[b * 64 + lane];
        unsigned long long pm;
        {   unsigned lo = postT[r * 32 + 2 * b], hi = postT[r * 32 + 2 * b + 1];
            pm = ((unsigned long long)(unsigned)__builtin_amdgcn_readfirstlane((int)hi) << 32)
               |  (unsigned long long)(unsigned)__builtin_amdgcn_readfirstlane((int)lo);
        }
        float dacc = fmaf(s0, myB0, u);
        float cj = 0.f;
        #pragma unroll
        for (int j = 0; j < 64; ++j) {
            if ((pm >> j) & 1ull) {            // wave-uniform branch
                float dot = __int_as_float(__builtin_amdgcn_readlane(__float_as_int(dacc), j));
                float pj  = __int_as_float(__builtin_amdgcn_readlane(__float_as_int(mypop), j));
                float c = LRC * inv_alpha;
                nu = fmaf(2.f * LRC, alpha * dot, fmaf(LRC * LRC, pj, nu));
                float t = fmaxf(nu, 1.f);
                alpha *= rsqrtf(t); inv_alpha *= sqrtf(t); nu = fminf(nu, 1.f);
                dacc = fmaf(c, Gd[j][lane], dacc);
                cj = (lane == j) ? c : cj;
            }
        }
        {   unsigned short hh = f2bf(cj);
            CHL[wid * 2 + 0][b * 64 + lane] = hh;
            CHL[wid * 2 + 1][b * 64 + lane] = f2bf(cj - bf2f(hh));
        }
        if (inv_alpha > 1e10f) {               // rescale: v = (hi+lo)*alpha, re-split
            #pragma unroll 1
            for (int kk = 0; kk <= b; ++kk) {
                float v = (bf2f(CHL[wid * 2 + 0][kk * 64 + lane])
                         + bf2f(CHL[wid * 2 + 1][kk * 64 + lane])) * alpha;
                unsigned short hh = f2bf(v);
                CHL[wid * 2 + 0][kk * 64 + lane] = hh;
                CHL[wid * 2 + 1][kk * 64 + lane] = f2bf(v - bf2f(hh));
            }
            s0 *= alpha; alpha = 1.f; inv_alpha = 1.f;
        }
    }
    if (lane == 0) alphaf[r] = alpha * s0;
    #pragma unroll
    for (int kk = 0; kk < 16; ++kk) {          // coef -> bf16 hi/lo directly
        float v = (bf2f(CHL[wid * 2 + 0][kk * 64 + lane])
                 + bf2f(CHL[wid * 2 + 1][kk * 64 + lane])) * alpha;
        unsigned short hh = f2bf(v);
        Ch[(long)r * SEQ + kk * 64 + lane] = hh;
        Cl[(long)r * SEQ + kk * 64 + lane] = f2bf(v - bf2f(hh));
    }
}

extern "C" void kernel_launch(void* const* d_in, const int* in_sizes, int n_in,
                              void* d_out, int out_size, void* d_ws, size_t ws_size,
                              hipStream_t stream) {
    const int*   tok     = (const int*)d_in[0];
    const float* sdr     = (const float*)d_in[1];
    const float* pos     = (const float*)d_in[2];
    const float* w_hippo = (const float*)d_in[3];
    const float* assoc   = (const float*)d_in[4];
    float* out = (float*)d_out;

    char* ws = (char*)d_ws;
    unsigned short* Hh  = (unsigned short*)(ws);                 // 0-4 MB; dead after fix64
    float*          G   = (float*)(ws);                          //   then G fp32 (4 MB)
    unsigned short* Wh  = (unsigned short*)(ws + (4l << 20));    // 4-12 MB
    unsigned short* Wl  = (unsigned short*)(ws + (12l << 20));   // 12-20 MB
    float*          dots= (float*)(ws + (20l << 20));            // 20-28 MB; then B0
    float*          B0f = dots;
    unsigned short* Xb  = (unsigned short*)(ws + (28l << 20));   // 28-32; dead after B0
    unsigned short* Gbh = Xb;                                    //   then G-bf16 hi (2 MB)
    unsigned short* Gbl = (unsigned short*)(ws + (30l << 20));   //   G-bf16 lo (2 MB)
    unsigned short* XbT = (unsigned short*)(ws + (32l << 20));   // 32-36 MB
    unsigned* preT   = (unsigned*)(ws + (36l << 20));            // 256 KB
    unsigned* postT  = (unsigned*)(ws + (36l << 20) + 262144);   // 256 KB
    float*    popf   = (float*)(ws + (36l << 20) + 524288);      // 4 KB
    float*    alphaf = (float*)(ws + (36l << 20) + 532480);      // 8 KB
    unsigned* cnt    = (unsigned*)(ws + (37l << 20));            // 4 B
    unsigned* list   = (unsigned*)(ws + (37l << 20) + 4096);     // 1 MB
    unsigned short* Sh  = (unsigned short*)(ws + (40l << 20));   // 40-48 MB (assoc bf16)
    unsigned short* Ch  = (unsigned short*)(ws + (48l << 20));   // 48-52 MB
    unsigned short* Cl  = (unsigned short*)(ws + (52l << 20));   // 52-56 MB

    k_hippo                <<<dim3(SEQ, 2), 256, 0, stream>>>(tok, sdr, pos, Hh, cnt);
    k_splits               <<<4096,         256, 0, stream>>>(w_hippo, Wh, Wl, assoc, Sh);
    k_mgemm<SPLIT_B, 64>   <<<dim3(32, 8),  256, 0, stream>>>(Hh, nullptr, Wh, Wl, dots,
                                                              1024, 2048, 2048, nullptr, nullptr);
    k_fixflag              <<<8192,         256, 0, stream>>>(dots, list, cnt);
    k_fix64                <<<2048,          64, 0, stream>>>(list, cnt, Hh, w_hippo, dots);
    k_packx                <<<384,          256, 0, stream>>>(dots, preT, popf, Xb, postT);
    k_transpose            <<<dim3(16, 32), 256, 0, stream>>>(Xb, XbT);
    k_mgemm<SPLIT_NONE, 64><<<dim3(16, 16), 256, 0, stream>>>(Sh, nullptr, Xb, nullptr, B0f,
                                                              2048, 1024, 2048, nullptr, nullptr);
    k_gram                 <<<SEQ,          256, 0, stream>>>(preT, G, Gbh, Gbl);
    k_scan2                <<<512,          256, 0, stream>>>(assoc, B0f, G, Gbh, Gbl,
                                                              postT, popf, Ch, Cl, alphaf);
    k_mgemm<SPLIT_A, 128>  <<<dim3(16, 16), 256, 0, stream>>>(Ch, Cl, XbT, nullptr, out,
                                                              2048, 2048, 1024, assoc, alphaf);
}